// Round 7
// baseline (282.364 us; speedup 1.0000x reference)
//
#include <hip/hip_runtime.h>

// Problem constants (fixed by setup_inputs)
#define NB 16
#define NQ 500
#define NC 256
#define NHW 64
#define MR 8000            // B*Q rows
#define KD 9216            // GEMM1 K = 36*256

typedef float f32x4 __attribute__((ext_vector_type(4)));
typedef __bf16 bf16x8 __attribute__((ext_vector_type(8)));
typedef unsigned short ushortx8 __attribute__((ext_vector_type(8)));
typedef unsigned short ushortx4 __attribute__((ext_vector_type(4)));

__device__ __forceinline__ unsigned short f2bf(float f) {
  unsigned int u = __builtin_bit_cast(unsigned int, f);
  u += 0x7fffu + ((u >> 16) & 1u);   // round-to-nearest-even
  return (unsigned short)(u >> 16);
}

// ---------------------------------------------------------------------------
// Kernel 1: points [B,Q,4,2]  (output 2, also kept in ws for the gather)
__global__ void k_points(const float* __restrict__ polys,
                         float* __restrict__ outp, float* __restrict__ wsp) {
  int n = blockIdx.x * 256 + threadIdx.x;
  if (n >= MR) return;
  f32x4 ca = *(const f32x4*)(polys + (size_t)n * 8);
  f32x4 cb = *(const f32x4*)(polys + (size_t)n * 8 + 4);
  const float av[4] = {0.0f, 0.33333334f, 0.66666669f, 1.0f};
#pragma unroll
  for (int s = 0; s < 4; ++s) {
    float a1 = av[s], a2 = a1 * a1, a3 = a2 * a1;
    float v0 = ca.x * a3 + ca.y * a2 + ca.z * a1 + ca.w;
    float v1 = cb.x * a3 + cb.y * a2 + cb.z * a1 + cb.w;
    float pt0 = 2.0f * v1 - 1.0f;
    float pt1 = 2.0f * v0 - 1.0f;
    outp[(size_t)n * 8 + s * 2 + 0] = pt0;
    outp[(size_t)n * 8 + s * 2 + 1] = pt1;
    wsp[(size_t)n * 8 + s * 2 + 0] = pt0;
    wsp[(size_t)n * 8 + s * 2 + 1] = pt1;
  }
}

// ---------------------------------------------------------------------------
// Kernel 2: permute Wk -> fragment-linear bf16 W2s[t>>3][o][t&7]
__global__ void k_permwk(const float* __restrict__ Wk,
                         unsigned short* __restrict__ W2s) {
  int tid = blockIdx.x * 256 + threadIdx.x;
  if (tid >= (KD / 8) * NC) return;      // 294912
  int o = tid & 255;
  int th = tid >> 8;                     // 0..1151  (= t>>3)
  int r = th >> 5;                       // sample slot 0..35
  int cbase = (th & 31) * 8;
  int np = r / 9;
  int kl = r - np * 9;
  int kk = kl / 3;
  int ll = kl - kk * 3;
  const float* src = Wk + (size_t)o * KD + (size_t)(np * 256 + cbase) * 9 + kk * 3 + ll;
  ushortx8 v;
#pragma unroll
  for (int j = 0; j < 8; ++j) v[j] = f2bf(src[(size_t)j * 9]);
  *(ushortx8*)(W2s + (size_t)th * 2048 + o * 8) = v;
}

// Kernel 2b: permute Wp -> fragment-linear bf16 WPs[j>>3][o][j&7]
__global__ void k_permwp(const float* __restrict__ Wp,
                         unsigned short* __restrict__ WPs) {
  int tid = blockIdx.x * 256 + threadIdx.x;
  if (tid >= 32 * 256) return;
  int o = tid & 255;
  int th = tid >> 8;
  const float* src = Wp + (size_t)o * 256 + th * 8;
  ushortx8 v;
#pragma unroll
  for (int j = 0; j < 8; ++j) v[j] = f2bf(src[j]);
  *(ushortx8*)(WPs + (size_t)th * 2048 + o * 8) = v;
}

// ---------------------------------------------------------------------------
// Kernel 3: fused gather + GEMM1, M-tile = 64 rows, split-K over sample slots.
// Decomposition: x=bid&7, kk8=(bid>>3)%K, j=bid/(8K), t=x+8j, guard t>=125;
// contiguous reindex tt = 16x - max(x-5,0) + j  (tiles_x = 16,16,16,16,16,15,15,15).
// Double-buffered A-LDS, ONE barrier per slot (distance-2 reuse barrier-safe).
// NEW: B-fragment register prefetch across the slot loop — pb0/pb1[kstep] hold
// slot r's fragments; at each kstep, after the MFMAs consume them, the loads
// for slot r+1 are issued into the same (statically-indexed) slots, giving
// ~one full slot of latency hiding for all B traffic.
__global__ __launch_bounds__(512, 4) void k_gemm1(
    const float* __restrict__ mem, const float* __restrict__ pts,
    const unsigned short* __restrict__ W2s, const float* __restrict__ bk,
    float* __restrict__ PART, unsigned short* __restrict__ CR1, int K) {
  __shared__ __align__(16) unsigned short Alds[2 * 2048 * 8];  // 64 KB

  const int bid = blockIdx.x;
  const int x = bid & 7;
  const int kk8 = (bid >> 3) % K;
  const int j = bid / (8 * K);
  const int t = x + 8 * j;
  if (t >= 125) return;
  const int tt = 16 * x - ((x > 5) ? (x - 5) : 0) + j;   // contiguous tile id
  const int nsl = 36 / K;
  const int r0 = kk8 * nsl;

  const int tid = threadIdx.x;
  const int n0 = tt * 64;
  const int lane = tid & 63;
  const int wave = tid >> 6;   // 0..7
  const int lr = lane & 15;
  const int ksub = lane >> 4;
  const int o0 = wave * 32;

  const int gchunk = tid & 31;
  const int gm0 = tid >> 5;    // 0..15 ; tasks handle rows gm0+16*task, task 0..3

  // per-task row/batch bases
  size_t boff[4];
  int nrow[4];
#pragma unroll
  for (int task = 0; task < 4; ++task) {
    nrow[task] = n0 + gm0 + 16 * task;
    boff[task] = (size_t)(nrow[task] / NQ) * (NHW * NHW * NC);
  }

  // B-fragment base for this wave (elements): chunk-dependent part added per use
  const unsigned short* const Wbase = W2s + (o0 + lr) * 8;

  f32x4 acc[4][2] = {};

  // --- B prefetch prologue: load slot r0's fragments ---
  ushortx8 pb0[8], pb1[8];
#pragma unroll
  for (int kstep = 0; kstep < 8; ++kstep) {
    const int chunk = kstep * 4 + ksub;
    const unsigned short* bp = Wbase + ((size_t)r0 * 32 + chunk) * 2048;
    pb0[kstep] = *(const ushortx8*)bp;
    pb1[kstep] = *(const ushortx8*)(bp + 128);
  }

  for (int r = r0; r < r0 + nsl; ++r) {
    const int s = r & 3;
    const int mm = r >> 2;
    // delta(a) = (1.5a-2)/32, exact in fp32; DHX = delta(mm/3), DWY = delta(mm%3)
    const int mdiv = (mm * 11) >> 5;          // mm/3 for mm in [0,9)
    const int mmod = mm - 3 * mdiv;
    const float dhx = (1.5f * (float)mdiv - 2.0f) * 0.03125f;
    const float dwy = (1.5f * (float)mmod - 2.0f) * 0.03125f;
    const int lbase = ((r - r0) & 1) * 2048;   // LDS buffer select
#pragma unroll 2
    for (int task = 0; task < 4; ++task) {
      const int m = gm0 + task * 16;
      const int n = nrow[task];
      const float* mb = mem + boff[task];
      const float p0 = pts[(size_t)n * 8 + s * 2 + 0];
      const float p1 = pts[(size_t)n * 8 + s * 2 + 1];
      // grid[...,0] (points[...,0]+delta_h) drives COLUMN; [...,1] drives ROW.
      const float gx = (p0 + dhx + 1.0f) * 0.5f * 63.0f;  // column
      const float gy = (p1 + dwy + 1.0f) * 0.5f * 63.0f;  // row
      const float x0f = floorf(gx), y0f = floorf(gy);
      const float fx = gx - x0f, fy = gy - y0f;
      const int ix0 = (int)x0f, iy0 = (int)y0f;
      const int ix1 = ix0 + 1, iy1 = iy0 + 1;
      const float vx0 = (ix0 >= 0 && ix0 < NHW) ? 1.0f : 0.0f;
      const float vx1 = (ix1 >= 0 && ix1 < NHW) ? 1.0f : 0.0f;
      const float vy0 = (iy0 >= 0 && iy0 < NHW) ? 1.0f : 0.0f;
      const float vy1 = (iy1 >= 0 && iy1 < NHW) ? 1.0f : 0.0f;
      const float w00 = (1.0f - fy) * (1.0f - fx) * vy0 * vx0;
      const float w01 = (1.0f - fy) * fx * vy0 * vx1;
      const float w10 = fy * (1.0f - fx) * vy1 * vx0;
      const float w11 = fy * fx * vy1 * vx1;
      const int cx0 = min(max(ix0, 0), NHW - 1), cx1 = min(max(ix1, 0), NHW - 1);
      const int cy0 = min(max(iy0, 0), NHW - 1), cy1 = min(max(iy1, 0), NHW - 1);
      const float* q00 = mb + (size_t)(cy0 * NHW + cx0) * NC + gchunk * 8;
      const float* q01 = mb + (size_t)(cy0 * NHW + cx1) * NC + gchunk * 8;
      const float* q10 = mb + (size_t)(cy1 * NHW + cx0) * NC + gchunk * 8;
      const float* q11 = mb + (size_t)(cy1 * NHW + cx1) * NC + gchunk * 8;
      f32x4 v00a = *(const f32x4*)q00, v00b = *(const f32x4*)(q00 + 4);
      f32x4 v01a = *(const f32x4*)q01, v01b = *(const f32x4*)(q01 + 4);
      f32x4 v10a = *(const f32x4*)q10, v10b = *(const f32x4*)(q10 + 4);
      f32x4 v11a = *(const f32x4*)q11, v11b = *(const f32x4*)(q11 + 4);
      f32x4 ra = v00a * w00 + v01a * w01 + v10a * w10 + v11a * w11;
      f32x4 rb = v00b * w00 + v01b * w01 + v10b * w10 + v11b * w11;
      ushortx8 pk;
      pk[0] = f2bf(ra.x); pk[1] = f2bf(ra.y); pk[2] = f2bf(ra.z); pk[3] = f2bf(ra.w);
      pk[4] = f2bf(rb.x); pk[5] = f2bf(rb.y); pk[6] = f2bf(rb.z); pk[7] = f2bf(rb.w);
      const int slot = lbase + gchunk * 64 + (m ^ (gchunk & 15));
      *(ushortx8*)(Alds + slot * 8) = pk;
    }
    __syncthreads();
    // next-slot B base (clamped: final iteration's prefetch is unused but must
    // stay in-bounds of W2s)
    const int rn = (r + 1 < 35) ? (r + 1) : 35;
#pragma unroll
    for (int kstep = 0; kstep < 8; ++kstep) {
      const int chunk = kstep * 4 + ksub;
      bf16x8 fb0 = __builtin_bit_cast(bf16x8, pb0[kstep]);
      bf16x8 fb1 = __builtin_bit_cast(bf16x8, pb1[kstep]);
#pragma unroll
      for (int mf = 0; mf < 4; ++mf) {
        const int sa = lbase + chunk * 64 + ((mf * 16 + lr) ^ (chunk & 15));
        ushortx8 ua = *(const ushortx8*)(Alds + sa * 8);
        bf16x8 fa = __builtin_bit_cast(bf16x8, ua);
        acc[mf][0] = __builtin_amdgcn_mfma_f32_16x16x32_bf16(fa, fb0, acc[mf][0], 0, 0, 0);
        acc[mf][1] = __builtin_amdgcn_mfma_f32_16x16x32_bf16(fa, fb1, acc[mf][1], 0, 0, 0);
      }
      // issue next slot's loads into the just-consumed registers
      const unsigned short* bpn = Wbase + ((size_t)rn * 32 + chunk) * 2048;
      pb0[kstep] = *(const ushortx8*)bpn;
      pb1[kstep] = *(const ushortx8*)(bpn + 128);
    }
  }
  // epilogue. C/D: col=lane&15, row=(lane>>4)*4+reg
  if (PART) {
    float* dst = PART + (size_t)kk8 * (MR * NC);
#pragma unroll
    for (int mf = 0; mf < 4; ++mf)
#pragma unroll
      for (int nf = 0; nf < 2; ++nf) {
        const int o = o0 + nf * 16 + lr;
#pragma unroll
        for (int reg = 0; reg < 4; ++reg) {
          const int mrow = mf * 16 + ksub * 4 + reg;
          dst[(size_t)(n0 + mrow) * 256 + o] = acc[mf][nf][reg];
        }
      }
  } else {
#pragma unroll
    for (int mf = 0; mf < 4; ++mf)
#pragma unroll
      for (int nf = 0; nf < 2; ++nf) {
        const int o = o0 + nf * 16 + lr;
        const float bko = bk[o];
#pragma unroll
        for (int reg = 0; reg < 4; ++reg) {
          const int mrow = mf * 16 + ksub * 4 + reg;
          float v = acc[mf][nf][reg] + bko;
          v = v > 0.0f ? v : 0.0f;
          CR1[(size_t)(n0 + mrow) * 256 + o] = f2bf(v);
        }
      }
  }
}

// ---------------------------------------------------------------------------
// Kernel 3b: reduce K partials + bias + relu -> bf16 CR1
__global__ __launch_bounds__(256) void k_red(
    const float* __restrict__ PART, const float* __restrict__ bk,
    unsigned short* __restrict__ CR1, int K) {
  int gid = blockIdx.x * 256 + threadIdx.x;     // one f32x4 (4 outputs) each
  size_t idx4 = (size_t)gid * 4;
  if (idx4 >= (size_t)MR * NC) return;
  f32x4 sum = *(const f32x4*)(PART + idx4);
  for (int k = 1; k < K; ++k)
    sum += *(const f32x4*)(PART + (size_t)k * (MR * NC) + idx4);
  f32x4 bv = *(const f32x4*)(bk + (idx4 & 255));
  sum += bv;
  ushortx4 pk;
#pragma unroll
  for (int e = 0; e < 4; ++e) {
    float v = sum[e] > 0.0f ? sum[e] : 0.0f;
    pk[e] = f2bf(v);
  }
  *(ushortx4*)(CR1 + idx4) = pk;
}

// ---------------------------------------------------------------------------
// Kernel 4: GEMM2  out[n,o] = sum_j CR1[n,j]*Wp[o,j] + bp[o]  (16-row tiles)
__global__ __launch_bounds__(256) void k_gemm2(
    const unsigned short* __restrict__ CR1, const unsigned short* __restrict__ WPs,
    const float* __restrict__ bp, float* __restrict__ outc) {
  const int tid = threadIdx.x;
  const int n0 = blockIdx.x * 16;
  const int lane = tid & 63;
  const int wave = tid >> 6;  // 0..3
  const int lr = lane & 15;
  const int ksub = lane >> 4;
  const int o0 = wave * 64;
  f32x4 acc[4] = {};
#pragma unroll
  for (int kstep = 0; kstep < 8; ++kstep) {
    const int t0 = kstep * 32 + ksub * 8;
    ushortx8 ua0 = *(const ushortx8*)(CR1 + (size_t)(n0 + lr) * 256 + t0);
    bf16x8 fa0 = __builtin_bit_cast(bf16x8, ua0);
    const int chunk = kstep * 4 + ksub;
#pragma unroll
    for (int nf = 0; nf < 4; ++nf) {
      ushortx8 ub = *(const ushortx8*)(WPs + (size_t)chunk * 2048 + (o0 + nf * 16 + lr) * 8);
      bf16x8 fb = __builtin_bit_cast(bf16x8, ub);
      acc[nf] = __builtin_amdgcn_mfma_f32_16x16x32_bf16(fa0, fb, acc[nf], 0, 0, 0);
    }
  }
#pragma unroll
  for (int nf = 0; nf < 4; ++nf) {
    const int o = o0 + nf * 16 + lr;
    const float bpo = bp[o];
#pragma unroll
    for (int reg = 0; reg < 4; ++reg) {
      const int mrow = ksub * 4 + reg;
      outc[(size_t)(n0 + mrow) * 256 + o] = acc[nf][reg] + bpo;
    }
  }
}

// ---------------------------------------------------------------------------
extern "C" void kernel_launch(void* const* d_in, const int* in_sizes, int n_in,
                              void* d_out, int out_size, void* d_ws, size_t ws_size,
                              hipStream_t stream) {
  (void)in_sizes; (void)n_in; (void)out_size;
  const float* polys = (const float*)d_in[1];
  const float* mem   = (const float*)d_in[2];
  const float* Wk    = (const float*)d_in[4];
  const float* bk    = (const float*)d_in[5];
  const float* Wp    = (const float*)d_in[6];
  const float* bp    = (const float*)d_in[7];
  float* out = (float*)d_out;
  float* out_pts = out + (size_t)MR * NC;   // second output: points

  // ws layout
  unsigned short* W2s = (unsigned short*)d_ws;                       // 4,718,592 B
  unsigned short* WPs = (unsigned short*)((char*)d_ws + 4718592);    //   131,072 B
  float*          PTS = (float*)((char*)d_ws + 4849664);             //   256,000 B
  unsigned short* CR1 = (unsigned short*)((char*)d_ws + 5105664);    // 4,096,000 B
  const size_t PART_OFF = 9201664;
  float*          PARTp = (float*)((char*)d_ws + PART_OFF);          // K*8,192,000 B

  int K = 1;
  if (ws_size >= PART_OFF + 4ull * 8192000ull) K = 4;
  else if (ws_size >= PART_OFF + 2ull * 8192000ull) K = 2;
  float* PART = (K > 1) ? PARTp : nullptr;

  hipLaunchKernelGGL(k_points, dim3(32), dim3(256), 0, stream, polys, out_pts, PTS);
  hipLaunchKernelGGL(k_permwk, dim3(1152), dim3(256), 0, stream, Wk, W2s);
  hipLaunchKernelGGL(k_permwp, dim3(32), dim3(256), 0, stream, Wp, WPs);
  hipLaunchKernelGGL(k_gemm1, dim3(128 * K), dim3(512), 0, stream,
                     mem, PTS, W2s, bk, PART, CR1, K);
  if (PART)
    hipLaunchKernelGGL(k_red, dim3(2000), dim3(256), 0, stream, PART, bk, CR1, K);
  hipLaunchKernelGGL(k_gemm2, dim3(500), dim3(256), 0, stream, CR1, WPs, bp, out);
}

// Round 8
// 270.097 us; speedup vs baseline: 1.0454x; 1.0454x over previous
//
#include <hip/hip_runtime.h>

// Problem constants (fixed by setup_inputs)
#define NB 16
#define NQ 500
#define NC 256
#define NHW 64
#define MR 8000            // B*Q rows
#define KD 9216            // GEMM1 K = 36*256

typedef float f32x4 __attribute__((ext_vector_type(4)));
typedef __bf16 bf16x8 __attribute__((ext_vector_type(8)));
typedef unsigned short ushortx8 __attribute__((ext_vector_type(8)));
typedef unsigned short ushortx4 __attribute__((ext_vector_type(4)));

__device__ __forceinline__ unsigned short f2bf(float f) {
  unsigned int u = __builtin_bit_cast(unsigned int, f);
  u += 0x7fffu + ((u >> 16) & 1u);   // round-to-nearest-even
  return (unsigned short)(u >> 16);
}

// ---------------------------------------------------------------------------
// Kernel 1: points [B,Q,4,2]  (output 2, also kept in ws for the gather)
__global__ void k_points(const float* __restrict__ polys,
                         float* __restrict__ outp, float* __restrict__ wsp) {
  int n = blockIdx.x * 256 + threadIdx.x;
  if (n >= MR) return;
  f32x4 ca = *(const f32x4*)(polys + (size_t)n * 8);
  f32x4 cb = *(const f32x4*)(polys + (size_t)n * 8 + 4);
  const float av[4] = {0.0f, 0.33333334f, 0.66666669f, 1.0f};
#pragma unroll
  for (int s = 0; s < 4; ++s) {
    float a1 = av[s], a2 = a1 * a1, a3 = a2 * a1;
    float v0 = ca.x * a3 + ca.y * a2 + ca.z * a1 + ca.w;
    float v1 = cb.x * a3 + cb.y * a2 + cb.z * a1 + cb.w;
    float pt0 = 2.0f * v1 - 1.0f;
    float pt1 = 2.0f * v0 - 1.0f;
    outp[(size_t)n * 8 + s * 2 + 0] = pt0;
    outp[(size_t)n * 8 + s * 2 + 1] = pt1;
    wsp[(size_t)n * 8 + s * 2 + 0] = pt0;
    wsp[(size_t)n * 8 + s * 2 + 1] = pt1;
  }
}

// ---------------------------------------------------------------------------
// Kernel 2: permute Wk -> fragment-linear bf16 W2s[t>>3][o][t&7]
__global__ void k_permwk(const float* __restrict__ Wk,
                         unsigned short* __restrict__ W2s) {
  int tid = blockIdx.x * 256 + threadIdx.x;
  if (tid >= (KD / 8) * NC) return;      // 294912
  int o = tid & 255;
  int th = tid >> 8;                     // 0..1151  (= t>>3)
  int r = th >> 5;                       // sample slot 0..35
  int cbase = (th & 31) * 8;
  int np = r / 9;
  int kl = r - np * 9;
  int kk = kl / 3;
  int ll = kl - kk * 3;
  const float* src = Wk + (size_t)o * KD + (size_t)(np * 256 + cbase) * 9 + kk * 3 + ll;
  ushortx8 v;
#pragma unroll
  for (int j = 0; j < 8; ++j) v[j] = f2bf(src[(size_t)j * 9]);
  *(ushortx8*)(W2s + (size_t)th * 2048 + o * 8) = v;
}

// Kernel 2b: permute Wp -> fragment-linear bf16 WPs[j>>3][o][j&7]
__global__ void k_permwp(const float* __restrict__ Wp,
                         unsigned short* __restrict__ WPs) {
  int tid = blockIdx.x * 256 + threadIdx.x;
  if (tid >= 32 * 256) return;
  int o = tid & 255;
  int th = tid >> 8;
  const float* src = Wp + (size_t)o * 256 + th * 8;
  ushortx8 v;
#pragma unroll
  for (int j = 0; j < 8; ++j) v[j] = f2bf(src[j]);
  *(ushortx8*)(WPs + (size_t)th * 2048 + o * 8) = v;
}

// ---------------------------------------------------------------------------
// Kernel 3: fused gather + GEMM1, M-tile = 64 rows, split-K over sample slots.
// Decomposition: x=bid&7, kk8=(bid>>3)%K, j=bid/(8K), t=x+8j, guard t>=125;
// contiguous reindex tt = 16x - max(x-5,0) + j (tiles_x = 16,16,16,16,16,15,15,15).
// SINGLE 32 KB A-buffer, two barriers per slot; occupancy (3+ blocks/CU at
// K=6) provides the cross-phase overlap instead of an intra-block dbuf.
// NOTE (round-7 lesson): no big register prefetch arrays — acc(32) + gather
// temps must stay under the launch_bounds VGPR cap or the compiler spills to
// scratch (493 MB of WRITE_SIZE last round).
__global__ __launch_bounds__(512, 6) void k_gemm1(
    const float* __restrict__ mem, const float* __restrict__ pts,
    const unsigned short* __restrict__ W2s, const float* __restrict__ bk,
    float* __restrict__ PART, unsigned short* __restrict__ CR1, int K) {
  __shared__ __align__(16) unsigned short Alds[2048 * 8];  // 32 KB

  const int bid = blockIdx.x;
  const int x = bid & 7;
  const int kk8 = (bid >> 3) % K;
  const int j = bid / (8 * K);
  const int t = x + 8 * j;
  if (t >= 125) return;
  const int tt = 16 * x - ((x > 5) ? (x - 5) : 0) + j;   // contiguous tile id
  const int nsl = 36 / K;
  const int r0 = kk8 * nsl;

  const int tid = threadIdx.x;
  const int n0 = tt * 64;
  const int lane = tid & 63;
  const int wave = tid >> 6;   // 0..7
  const int lr = lane & 15;
  const int ksub = lane >> 4;
  const int o0 = wave * 32;

  const int gchunk = tid & 31;
  const int gm0 = tid >> 5;    // 0..15 ; tasks handle rows gm0+16*task, task 0..3

  // per-task row/batch bases
  size_t boff[4];
  int nrow[4];
#pragma unroll
  for (int task = 0; task < 4; ++task) {
    nrow[task] = n0 + gm0 + 16 * task;
    boff[task] = (size_t)(nrow[task] / NQ) * (NHW * NHW * NC);
  }

  f32x4 acc[4][2] = {};

  for (int r = r0; r < r0 + nsl; ++r) {
    const int s = r & 3;
    const int mm = r >> 2;
    // delta(a) = (1.5a-2)/32, exact in fp32; DHX = delta(mm/3), DWY = delta(mm%3)
    const int mdiv = (mm * 11) >> 5;          // mm/3 for mm in [0,9)
    const int mmod = mm - 3 * mdiv;
    const float dhx = (1.5f * (float)mdiv - 2.0f) * 0.03125f;
    const float dwy = (1.5f * (float)mmod - 2.0f) * 0.03125f;
    if (r != r0) __syncthreads();   // protect Alds reuse (prev MFMA done)
#pragma unroll 2
    for (int task = 0; task < 4; ++task) {
      const int m = gm0 + task * 16;
      const int n = nrow[task];
      const float* mb = mem + boff[task];
      const float p0 = pts[(size_t)n * 8 + s * 2 + 0];
      const float p1 = pts[(size_t)n * 8 + s * 2 + 1];
      // grid[...,0] (points[...,0]+delta_h) drives COLUMN; [...,1] drives ROW.
      const float gx = (p0 + dhx + 1.0f) * 0.5f * 63.0f;  // column
      const float gy = (p1 + dwy + 1.0f) * 0.5f * 63.0f;  // row
      const float x0f = floorf(gx), y0f = floorf(gy);
      const float fx = gx - x0f, fy = gy - y0f;
      const int ix0 = (int)x0f, iy0 = (int)y0f;
      const int ix1 = ix0 + 1, iy1 = iy0 + 1;
      const float vx0 = (ix0 >= 0 && ix0 < NHW) ? 1.0f : 0.0f;
      const float vx1 = (ix1 >= 0 && ix1 < NHW) ? 1.0f : 0.0f;
      const float vy0 = (iy0 >= 0 && iy0 < NHW) ? 1.0f : 0.0f;
      const float vy1 = (iy1 >= 0 && iy1 < NHW) ? 1.0f : 0.0f;
      const float w00 = (1.0f - fy) * (1.0f - fx) * vy0 * vx0;
      const float w01 = (1.0f - fy) * fx * vy0 * vx1;
      const float w10 = fy * (1.0f - fx) * vy1 * vx0;
      const float w11 = fy * fx * vy1 * vx1;
      const int cx0 = min(max(ix0, 0), NHW - 1), cx1 = min(max(ix1, 0), NHW - 1);
      const int cy0 = min(max(iy0, 0), NHW - 1), cy1 = min(max(iy1, 0), NHW - 1);
      const float* q00 = mb + (size_t)(cy0 * NHW + cx0) * NC + gchunk * 8;
      const float* q01 = mb + (size_t)(cy0 * NHW + cx1) * NC + gchunk * 8;
      const float* q10 = mb + (size_t)(cy1 * NHW + cx0) * NC + gchunk * 8;
      const float* q11 = mb + (size_t)(cy1 * NHW + cx1) * NC + gchunk * 8;
      f32x4 v00a = *(const f32x4*)q00, v00b = *(const f32x4*)(q00 + 4);
      f32x4 v01a = *(const f32x4*)q01, v01b = *(const f32x4*)(q01 + 4);
      f32x4 v10a = *(const f32x4*)q10, v10b = *(const f32x4*)(q10 + 4);
      f32x4 v11a = *(const f32x4*)q11, v11b = *(const f32x4*)(q11 + 4);
      f32x4 ra = v00a * w00 + v01a * w01 + v10a * w10 + v11a * w11;
      f32x4 rb = v00b * w00 + v01b * w01 + v10b * w10 + v11b * w11;
      ushortx8 pk;
      pk[0] = f2bf(ra.x); pk[1] = f2bf(ra.y); pk[2] = f2bf(ra.z); pk[3] = f2bf(ra.w);
      pk[4] = f2bf(rb.x); pk[5] = f2bf(rb.y); pk[6] = f2bf(rb.z); pk[7] = f2bf(rb.w);
      const int slot = gchunk * 64 + (m ^ (gchunk & 15));
      *(ushortx8*)(Alds + slot * 8) = pk;
    }
    __syncthreads();
    const size_t rbase = (size_t)r * 32;
#pragma unroll
    for (int kstep = 0; kstep < 8; ++kstep) {
      const int chunk = kstep * 4 + ksub;
      const unsigned short* bp = W2s + (rbase + chunk) * 2048 + (o0 + lr) * 8;
      ushortx8 ub0 = *(const ushortx8*)bp;
      ushortx8 ub1 = *(const ushortx8*)(bp + 128);
      bf16x8 fb0 = __builtin_bit_cast(bf16x8, ub0);
      bf16x8 fb1 = __builtin_bit_cast(bf16x8, ub1);
#pragma unroll
      for (int mf = 0; mf < 4; ++mf) {
        const int sa = chunk * 64 + ((mf * 16 + lr) ^ (chunk & 15));
        ushortx8 ua = *(const ushortx8*)(Alds + sa * 8);
        bf16x8 fa = __builtin_bit_cast(bf16x8, ua);
        acc[mf][0] = __builtin_amdgcn_mfma_f32_16x16x32_bf16(fa, fb0, acc[mf][0], 0, 0, 0);
        acc[mf][1] = __builtin_amdgcn_mfma_f32_16x16x32_bf16(fa, fb1, acc[mf][1], 0, 0, 0);
      }
    }
  }
  // epilogue. C/D: col=lane&15, row=(lane>>4)*4+reg
  if (PART) {
    float* dst = PART + (size_t)kk8 * (MR * NC);
#pragma unroll
    for (int mf = 0; mf < 4; ++mf)
#pragma unroll
      for (int nf = 0; nf < 2; ++nf) {
        const int o = o0 + nf * 16 + lr;
#pragma unroll
        for (int reg = 0; reg < 4; ++reg) {
          const int mrow = mf * 16 + ksub * 4 + reg;
          dst[(size_t)(n0 + mrow) * 256 + o] = acc[mf][nf][reg];
        }
      }
  } else {
#pragma unroll
    for (int mf = 0; mf < 4; ++mf)
#pragma unroll
      for (int nf = 0; nf < 2; ++nf) {
        const int o = o0 + nf * 16 + lr;
        const float bko = bk[o];
#pragma unroll
        for (int reg = 0; reg < 4; ++reg) {
          const int mrow = mf * 16 + ksub * 4 + reg;
          float v = acc[mf][nf][reg] + bko;
          v = v > 0.0f ? v : 0.0f;
          CR1[(size_t)(n0 + mrow) * 256 + o] = f2bf(v);
        }
      }
  }
}

// ---------------------------------------------------------------------------
// Kernel 3b: reduce K partials + bias + relu -> bf16 CR1
__global__ __launch_bounds__(256) void k_red(
    const float* __restrict__ PART, const float* __restrict__ bk,
    unsigned short* __restrict__ CR1, int K) {
  int gid = blockIdx.x * 256 + threadIdx.x;     // one f32x4 (4 outputs) each
  size_t idx4 = (size_t)gid * 4;
  if (idx4 >= (size_t)MR * NC) return;
  f32x4 sum = *(const f32x4*)(PART + idx4);
  for (int k = 1; k < K; ++k)
    sum += *(const f32x4*)(PART + (size_t)k * (MR * NC) + idx4);
  f32x4 bv = *(const f32x4*)(bk + (idx4 & 255));
  sum += bv;
  ushortx4 pk;
#pragma unroll
  for (int e = 0; e < 4; ++e) {
    float v = sum[e] > 0.0f ? sum[e] : 0.0f;
    pk[e] = f2bf(v);
  }
  *(ushortx4*)(CR1 + idx4) = pk;
}

// ---------------------------------------------------------------------------
// Kernel 4: GEMM2  out[n,o] = sum_j CR1[n,j]*Wp[o,j] + bp[o]  (16-row tiles)
__global__ __launch_bounds__(256) void k_gemm2(
    const unsigned short* __restrict__ CR1, const unsigned short* __restrict__ WPs,
    const float* __restrict__ bp, float* __restrict__ outc) {
  const int tid = threadIdx.x;
  const int n0 = blockIdx.x * 16;
  const int lane = tid & 63;
  const int wave = tid >> 6;  // 0..3
  const int lr = lane & 15;
  const int ksub = lane >> 4;
  const int o0 = wave * 64;
  f32x4 acc[4] = {};
#pragma unroll
  for (int kstep = 0; kstep < 8; ++kstep) {
    const int t0 = kstep * 32 + ksub * 8;
    ushortx8 ua0 = *(const ushortx8*)(CR1 + (size_t)(n0 + lr) * 256 + t0);
    bf16x8 fa0 = __builtin_bit_cast(bf16x8, ua0);
    const int chunk = kstep * 4 + ksub;
#pragma unroll
    for (int nf = 0; nf < 4; ++nf) {
      ushortx8 ub = *(const ushortx8*)(WPs + (size_t)chunk * 2048 + (o0 + nf * 16 + lr) * 8);
      bf16x8 fb = __builtin_bit_cast(bf16x8, ub);
      acc[nf] = __builtin_amdgcn_mfma_f32_16x16x32_bf16(fa0, fb, acc[nf], 0, 0, 0);
    }
  }
#pragma unroll
  for (int nf = 0; nf < 4; ++nf) {
    const int o = o0 + nf * 16 + lr;
    const float bpo = bp[o];
#pragma unroll
    for (int reg = 0; reg < 4; ++reg) {
      const int mrow = ksub * 4 + reg;
      outc[(size_t)(n0 + mrow) * 256 + o] = acc[nf][reg] + bpo;
    }
  }
}

// ---------------------------------------------------------------------------
extern "C" void kernel_launch(void* const* d_in, const int* in_sizes, int n_in,
                              void* d_out, int out_size, void* d_ws, size_t ws_size,
                              hipStream_t stream) {
  (void)in_sizes; (void)n_in; (void)out_size;
  const float* polys = (const float*)d_in[1];
  const float* mem   = (const float*)d_in[2];
  const float* Wk    = (const float*)d_in[4];
  const float* bk    = (const float*)d_in[5];
  const float* Wp    = (const float*)d_in[6];
  const float* bp    = (const float*)d_in[7];
  float* out = (float*)d_out;
  float* out_pts = out + (size_t)MR * NC;   // second output: points

  // ws layout
  unsigned short* W2s = (unsigned short*)d_ws;                       // 4,718,592 B
  unsigned short* WPs = (unsigned short*)((char*)d_ws + 4718592);    //   131,072 B
  float*          PTS = (float*)((char*)d_ws + 4849664);             //   256,000 B
  unsigned short* CR1 = (unsigned short*)((char*)d_ws + 5105664);    // 4,096,000 B
  const size_t PART_OFF = 9201664;
  const size_t PART_SZ = 8192000ull;
  float*          PARTp = (float*)((char*)d_ws + PART_OFF);          // K*PART_SZ

  int K = 1;
  if (ws_size >= PART_OFF + 6ull * PART_SZ) K = 6;
  else if (ws_size >= PART_OFF + 4ull * PART_SZ) K = 4;
  else if (ws_size >= PART_OFF + 2ull * PART_SZ) K = 2;
  float* PART = (K > 1) ? PARTp : nullptr;

  hipLaunchKernelGGL(k_points, dim3(32), dim3(256), 0, stream, polys, out_pts, PTS);
  hipLaunchKernelGGL(k_permwk, dim3(1152), dim3(256), 0, stream, Wk, W2s);
  hipLaunchKernelGGL(k_permwp, dim3(32), dim3(256), 0, stream, Wp, WPs);
  hipLaunchKernelGGL(k_gemm1, dim3(128 * K), dim3(512), 0, stream,
                     mem, PTS, W2s, bk, PART, CR1, K);
  if (PART)
    hipLaunchKernelGGL(k_red, dim3(2000), dim3(256), 0, stream, PART, bk, CR1, K);
  hipLaunchKernelGGL(k_gemm2, dim3(500), dim3(256), 0, stream, CR1, WPs, bp, out);
}

// Round 9
// 135.951 us; speedup vs baseline: 2.0770x; 1.9867x over previous
//
#include <hip/hip_runtime.h>

// Problem constants (fixed by setup_inputs)
#define NB 16
#define NQ 500
#define NC 256
#define NHW 64
#define MR 8000            // B*Q rows
#define KD 9216            // GEMM1 K = 36*256

typedef float f32x4 __attribute__((ext_vector_type(4)));
typedef __bf16 bf16x8 __attribute__((ext_vector_type(8)));
typedef unsigned short ushortx8 __attribute__((ext_vector_type(8)));
typedef unsigned short ushortx4 __attribute__((ext_vector_type(4)));

__device__ __forceinline__ unsigned short f2bf(float f) {
  unsigned int u = __builtin_bit_cast(unsigned int, f);
  u += 0x7fffu + ((u >> 16) & 1u);   // round-to-nearest-even
  return (unsigned short)(u >> 16);
}

// ---------------------------------------------------------------------------
// Kernel 1: points [B,Q,4,2]  (output 2, also kept in ws for the gather)
__global__ void k_points(const float* __restrict__ polys,
                         float* __restrict__ outp, float* __restrict__ wsp) {
  int n = blockIdx.x * 256 + threadIdx.x;
  if (n >= MR) return;
  f32x4 ca = *(const f32x4*)(polys + (size_t)n * 8);
  f32x4 cb = *(const f32x4*)(polys + (size_t)n * 8 + 4);
  const float av[4] = {0.0f, 0.33333334f, 0.66666669f, 1.0f};
#pragma unroll
  for (int s = 0; s < 4; ++s) {
    float a1 = av[s], a2 = a1 * a1, a3 = a2 * a1;
    float v0 = ca.x * a3 + ca.y * a2 + ca.z * a1 + ca.w;
    float v1 = cb.x * a3 + cb.y * a2 + cb.z * a1 + cb.w;
    float pt0 = 2.0f * v1 - 1.0f;
    float pt1 = 2.0f * v0 - 1.0f;
    outp[(size_t)n * 8 + s * 2 + 0] = pt0;
    outp[(size_t)n * 8 + s * 2 + 1] = pt1;
    wsp[(size_t)n * 8 + s * 2 + 0] = pt0;
    wsp[(size_t)n * 8 + s * 2 + 1] = pt1;
  }
}

// ---------------------------------------------------------------------------
// Kernel 2: permute Wk -> fragment-linear bf16 W2s[t>>3][o][t&7]
__global__ void k_permwk(const float* __restrict__ Wk,
                         unsigned short* __restrict__ W2s) {
  int tid = blockIdx.x * 256 + threadIdx.x;
  if (tid >= (KD / 8) * NC) return;      // 294912
  int o = tid & 255;
  int th = tid >> 8;                     // 0..1151  (= t>>3)
  int r = th >> 5;                       // sample slot 0..35
  int cbase = (th & 31) * 8;
  int np = r / 9;
  int kl = r - np * 9;
  int kk = kl / 3;
  int ll = kl - kk * 3;
  const float* src = Wk + (size_t)o * KD + (size_t)(np * 256 + cbase) * 9 + kk * 3 + ll;
  ushortx8 v;
#pragma unroll
  for (int j = 0; j < 8; ++j) v[j] = f2bf(src[(size_t)j * 9]);
  *(ushortx8*)(W2s + (size_t)th * 2048 + o * 8) = v;
}

// Kernel 2b: permute Wp -> fragment-linear bf16 WPs[j>>3][o][j&7]
__global__ void k_permwp(const float* __restrict__ Wp,
                         unsigned short* __restrict__ WPs) {
  int tid = blockIdx.x * 256 + threadIdx.x;
  if (tid >= 32 * 256) return;
  int o = tid & 255;
  int th = tid >> 8;
  const float* src = Wp + (size_t)o * 256 + th * 8;
  ushortx8 v;
#pragma unroll
  for (int j = 0; j < 8; ++j) v[j] = f2bf(src[j]);
  *(ushortx8*)(WPs + (size_t)th * 2048 + o * 8) = v;
}

// ---------------------------------------------------------------------------
// Kernel 3: fused gather + GEMM1, M-tile = 64 rows, split-K over sample slots.
// Decomposition: x=bid&7, kk8=(bid>>3)%K, j=bid/(8K), t=x+8j, guard t>=125;
// contiguous reindex tt = 16x - max(x-5,0) + j (tiles_x = 16,16,16,16,16,15,15,15).
// SINGLE 32 KB A-buffer, two barriers per slot; occupancy (3-4 blocks/CU at
// K=6) provides the cross-phase overlap instead of an intra-block dbuf.
// ROUND-8/9 LESSON: launch_bounds min-waves MUST stay at 4 for this body.
// (512,6) made the allocator emit a 40-VGPR + scratch-spill build (486 MB of
// scratch writes, 2.6x slowdown). (512,4) compiles this family to 52-84 VGPR
// with zero spill; occupancy then comes from the 32 KB LDS + 750-block grid.
__global__ __launch_bounds__(512, 4) void k_gemm1(
    const float* __restrict__ mem, const float* __restrict__ pts,
    const unsigned short* __restrict__ W2s, const float* __restrict__ bk,
    float* __restrict__ PART, unsigned short* __restrict__ CR1, int K) {
  __shared__ __align__(16) unsigned short Alds[2048 * 8];  // 32 KB

  const int bid = blockIdx.x;
  const int x = bid & 7;
  const int kk8 = (bid >> 3) % K;
  const int j = bid / (8 * K);
  const int t = x + 8 * j;
  if (t >= 125) return;
  const int tt = 16 * x - ((x > 5) ? (x - 5) : 0) + j;   // contiguous tile id
  const int nsl = 36 / K;
  const int r0 = kk8 * nsl;

  const int tid = threadIdx.x;
  const int n0 = tt * 64;
  const int lane = tid & 63;
  const int wave = tid >> 6;   // 0..7
  const int lr = lane & 15;
  const int ksub = lane >> 4;
  const int o0 = wave * 32;

  const int gchunk = tid & 31;
  const int gm0 = tid >> 5;    // 0..15 ; tasks handle rows gm0+16*task, task 0..3

  // per-task row/batch bases
  size_t boff[4];
  int nrow[4];
#pragma unroll
  for (int task = 0; task < 4; ++task) {
    nrow[task] = n0 + gm0 + 16 * task;
    boff[task] = (size_t)(nrow[task] / NQ) * (NHW * NHW * NC);
  }

  f32x4 acc[4][2] = {};

  for (int r = r0; r < r0 + nsl; ++r) {
    const int s = r & 3;
    const int mm = r >> 2;
    // delta(a) = (1.5a-2)/32, exact in fp32; DHX = delta(mm/3), DWY = delta(mm%3)
    const int mdiv = (mm * 11) >> 5;          // mm/3 for mm in [0,9)
    const int mmod = mm - 3 * mdiv;
    const float dhx = (1.5f * (float)mdiv - 2.0f) * 0.03125f;
    const float dwy = (1.5f * (float)mmod - 2.0f) * 0.03125f;
    if (r != r0) __syncthreads();   // protect Alds reuse (prev MFMA done)
#pragma unroll 2
    for (int task = 0; task < 4; ++task) {
      const int m = gm0 + task * 16;
      const int n = nrow[task];
      const float* mb = mem + boff[task];
      const float p0 = pts[(size_t)n * 8 + s * 2 + 0];
      const float p1 = pts[(size_t)n * 8 + s * 2 + 1];
      // grid[...,0] (points[...,0]+delta_h) drives COLUMN; [...,1] drives ROW.
      const float gx = (p0 + dhx + 1.0f) * 0.5f * 63.0f;  // column
      const float gy = (p1 + dwy + 1.0f) * 0.5f * 63.0f;  // row
      const float x0f = floorf(gx), y0f = floorf(gy);
      const float fx = gx - x0f, fy = gy - y0f;
      const int ix0 = (int)x0f, iy0 = (int)y0f;
      const int ix1 = ix0 + 1, iy1 = iy0 + 1;
      const float vx0 = (ix0 >= 0 && ix0 < NHW) ? 1.0f : 0.0f;
      const float vx1 = (ix1 >= 0 && ix1 < NHW) ? 1.0f : 0.0f;
      const float vy0 = (iy0 >= 0 && iy0 < NHW) ? 1.0f : 0.0f;
      const float vy1 = (iy1 >= 0 && iy1 < NHW) ? 1.0f : 0.0f;
      const float w00 = (1.0f - fy) * (1.0f - fx) * vy0 * vx0;
      const float w01 = (1.0f - fy) * fx * vy0 * vx1;
      const float w10 = fy * (1.0f - fx) * vy1 * vx0;
      const float w11 = fy * fx * vy1 * vx1;
      const int cx0 = min(max(ix0, 0), NHW - 1), cx1 = min(max(ix1, 0), NHW - 1);
      const int cy0 = min(max(iy0, 0), NHW - 1), cy1 = min(max(iy1, 0), NHW - 1);
      const float* q00 = mb + (size_t)(cy0 * NHW + cx0) * NC + gchunk * 8;
      const float* q01 = mb + (size_t)(cy0 * NHW + cx1) * NC + gchunk * 8;
      const float* q10 = mb + (size_t)(cy1 * NHW + cx0) * NC + gchunk * 8;
      const float* q11 = mb + (size_t)(cy1 * NHW + cx1) * NC + gchunk * 8;
      f32x4 v00a = *(const f32x4*)q00, v00b = *(const f32x4*)(q00 + 4);
      f32x4 v01a = *(const f32x4*)q01, v01b = *(const f32x4*)(q01 + 4);
      f32x4 v10a = *(const f32x4*)q10, v10b = *(const f32x4*)(q10 + 4);
      f32x4 v11a = *(const f32x4*)q11, v11b = *(const f32x4*)(q11 + 4);
      f32x4 ra = v00a * w00 + v01a * w01 + v10a * w10 + v11a * w11;
      f32x4 rb = v00b * w00 + v01b * w01 + v10b * w10 + v11b * w11;
      ushortx8 pk;
      pk[0] = f2bf(ra.x); pk[1] = f2bf(ra.y); pk[2] = f2bf(ra.z); pk[3] = f2bf(ra.w);
      pk[4] = f2bf(rb.x); pk[5] = f2bf(rb.y); pk[6] = f2bf(rb.z); pk[7] = f2bf(rb.w);
      const int slot = gchunk * 64 + (m ^ (gchunk & 15));
      *(ushortx8*)(Alds + slot * 8) = pk;
    }
    __syncthreads();
    const size_t rbase = (size_t)r * 32;
#pragma unroll
    for (int kstep = 0; kstep < 8; ++kstep) {
      const int chunk = kstep * 4 + ksub;
      const unsigned short* bp = W2s + (rbase + chunk) * 2048 + (o0 + lr) * 8;
      ushortx8 ub0 = *(const ushortx8*)bp;
      ushortx8 ub1 = *(const ushortx8*)(bp + 128);
      bf16x8 fb0 = __builtin_bit_cast(bf16x8, ub0);
      bf16x8 fb1 = __builtin_bit_cast(bf16x8, ub1);
#pragma unroll
      for (int mf = 0; mf < 4; ++mf) {
        const int sa = chunk * 64 + ((mf * 16 + lr) ^ (chunk & 15));
        ushortx8 ua = *(const ushortx8*)(Alds + sa * 8);
        bf16x8 fa = __builtin_bit_cast(bf16x8, ua);
        acc[mf][0] = __builtin_amdgcn_mfma_f32_16x16x32_bf16(fa, fb0, acc[mf][0], 0, 0, 0);
        acc[mf][1] = __builtin_amdgcn_mfma_f32_16x16x32_bf16(fa, fb1, acc[mf][1], 0, 0, 0);
      }
    }
  }
  // epilogue. C/D: col=lane&15, row=(lane>>4)*4+reg
  if (PART) {
    float* dst = PART + (size_t)kk8 * (MR * NC);
#pragma unroll
    for (int mf = 0; mf < 4; ++mf)
#pragma unroll
      for (int nf = 0; nf < 2; ++nf) {
        const int o = o0 + nf * 16 + lr;
#pragma unroll
        for (int reg = 0; reg < 4; ++reg) {
          const int mrow = mf * 16 + ksub * 4 + reg;
          dst[(size_t)(n0 + mrow) * 256 + o] = acc[mf][nf][reg];
        }
      }
  } else {
#pragma unroll
    for (int mf = 0; mf < 4; ++mf)
#pragma unroll
      for (int nf = 0; nf < 2; ++nf) {
        const int o = o0 + nf * 16 + lr;
        const float bko = bk[o];
#pragma unroll
        for (int reg = 0; reg < 4; ++reg) {
          const int mrow = mf * 16 + ksub * 4 + reg;
          float v = acc[mf][nf][reg] + bko;
          v = v > 0.0f ? v : 0.0f;
          CR1[(size_t)(n0 + mrow) * 256 + o] = f2bf(v);
        }
      }
  }
}

// ---------------------------------------------------------------------------
// Kernel 3b: reduce K partials + bias + relu -> bf16 CR1
__global__ __launch_bounds__(256) void k_red(
    const float* __restrict__ PART, const float* __restrict__ bk,
    unsigned short* __restrict__ CR1, int K) {
  int gid = blockIdx.x * 256 + threadIdx.x;     // one f32x4 (4 outputs) each
  size_t idx4 = (size_t)gid * 4;
  if (idx4 >= (size_t)MR * NC) return;
  f32x4 sum = *(const f32x4*)(PART + idx4);
  for (int k = 1; k < K; ++k)
    sum += *(const f32x4*)(PART + (size_t)k * (MR * NC) + idx4);
  f32x4 bv = *(const f32x4*)(bk + (idx4 & 255));
  sum += bv;
  ushortx4 pk;
#pragma unroll
  for (int e = 0; e < 4; ++e) {
    float v = sum[e] > 0.0f ? sum[e] : 0.0f;
    pk[e] = f2bf(v);
  }
  *(ushortx4*)(CR1 + idx4) = pk;
}

// ---------------------------------------------------------------------------
// Kernel 4: GEMM2  out[n,o] = sum_j CR1[n,j]*Wp[o,j] + bp[o]  (16-row tiles)
__global__ __launch_bounds__(256) void k_gemm2(
    const unsigned short* __restrict__ CR1, const unsigned short* __restrict__ WPs,
    const float* __restrict__ bp, float* __restrict__ outc) {
  const int tid = threadIdx.x;
  const int n0 = blockIdx.x * 16;
  const int lane = tid & 63;
  const int wave = tid >> 6;  // 0..3
  const int lr = lane & 15;
  const int ksub = lane >> 4;
  const int o0 = wave * 64;
  f32x4 acc[4] = {};
#pragma unroll
  for (int kstep = 0; kstep < 8; ++kstep) {
    const int t0 = kstep * 32 + ksub * 8;
    ushortx8 ua0 = *(const ushortx8*)(CR1 + (size_t)(n0 + lr) * 256 + t0);
    bf16x8 fa0 = __builtin_bit_cast(bf16x8, ua0);
    const int chunk = kstep * 4 + ksub;
#pragma unroll
    for (int nf = 0; nf < 4; ++nf) {
      ushortx8 ub = *(const ushortx8*)(WPs + (size_t)chunk * 2048 + (o0 + nf * 16 + lr) * 8);
      bf16x8 fb = __builtin_bit_cast(bf16x8, ub);
      acc[nf] = __builtin_amdgcn_mfma_f32_16x16x32_bf16(fa0, fb, acc[nf], 0, 0, 0);
    }
  }
#pragma unroll
  for (int nf = 0; nf < 4; ++nf) {
    const int o = o0 + nf * 16 + lr;
    const float bpo = bp[o];
#pragma unroll
    for (int reg = 0; reg < 4; ++reg) {
      const int mrow = ksub * 4 + reg;
      outc[(size_t)(n0 + mrow) * 256 + o] = acc[nf][reg] + bpo;
    }
  }
}

// ---------------------------------------------------------------------------
extern "C" void kernel_launch(void* const* d_in, const int* in_sizes, int n_in,
                              void* d_out, int out_size, void* d_ws, size_t ws_size,
                              hipStream_t stream) {
  (void)in_sizes; (void)n_in; (void)out_size;
  const float* polys = (const float*)d_in[1];
  const float* mem   = (const float*)d_in[2];
  const float* Wk    = (const float*)d_in[4];
  const float* bk    = (const float*)d_in[5];
  const float* Wp    = (const float*)d_in[6];
  const float* bp    = (const float*)d_in[7];
  float* out = (float*)d_out;
  float* out_pts = out + (size_t)MR * NC;   // second output: points

  // ws layout
  unsigned short* W2s = (unsigned short*)d_ws;                       // 4,718,592 B
  unsigned short* WPs = (unsigned short*)((char*)d_ws + 4718592);    //   131,072 B
  float*          PTS = (float*)((char*)d_ws + 4849664);             //   256,000 B
  unsigned short* CR1 = (unsigned short*)((char*)d_ws + 5105664);    // 4,096,000 B
  const size_t PART_OFF = 9201664;
  const size_t PART_SZ = 8192000ull;
  float*          PARTp = (float*)((char*)d_ws + PART_OFF);          // K*PART_SZ

  int K = 1;
  if (ws_size >= PART_OFF + 6ull * PART_SZ) K = 6;
  else if (ws_size >= PART_OFF + 4ull * PART_SZ) K = 4;
  else if (ws_size >= PART_OFF + 2ull * PART_SZ) K = 2;
  float* PART = (K > 1) ? PARTp : nullptr;

  hipLaunchKernelGGL(k_points, dim3(32), dim3(256), 0, stream, polys, out_pts, PTS);
  hipLaunchKernelGGL(k_permwk, dim3(1152), dim3(256), 0, stream, Wk, W2s);
  hipLaunchKernelGGL(k_permwp, dim3(32), dim3(256), 0, stream, Wp, WPs);
  hipLaunchKernelGGL(k_gemm1, dim3(128 * K), dim3(512), 0, stream,
                     mem, PTS, W2s, bk, PART, CR1, K);
  if (PART)
    hipLaunchKernelGGL(k_red, dim3(2000), dim3(256), 0, stream, PART, bk, CR1, K);
  hipLaunchKernelGGL(k_gemm2, dim3(500), dim3(256), 0, stream, CR1, WPs, bp, out);
}

// Round 10
// 121.156 us; speedup vs baseline: 2.3306x; 1.1221x over previous
//
#include <hip/hip_runtime.h>

// Problem constants (fixed by setup_inputs)
#define NB 16
#define NQ 500
#define NC 256
#define NHW 64
#define MR 8000            // B*Q rows
#define KD 9216            // GEMM1 K = 36*256

typedef float f32x4 __attribute__((ext_vector_type(4)));
typedef __bf16 bf16x8 __attribute__((ext_vector_type(8)));
typedef unsigned short ushortx8 __attribute__((ext_vector_type(8)));
typedef unsigned short ushortx4 __attribute__((ext_vector_type(4)));

__device__ __forceinline__ unsigned short f2bf(float f) {
  unsigned int u = __builtin_bit_cast(unsigned int, f);
  u += 0x7fffu + ((u >> 16) & 1u);   // round-to-nearest-even
  return (unsigned short)(u >> 16);
}

// ---------------------------------------------------------------------------
// Kernel 1: points [B,Q,4,2]  (output 2, also kept in ws for the gather)
__global__ void k_points(const float* __restrict__ polys,
                         float* __restrict__ outp, float* __restrict__ wsp) {
  int n = blockIdx.x * 256 + threadIdx.x;
  if (n >= MR) return;
  f32x4 ca = *(const f32x4*)(polys + (size_t)n * 8);
  f32x4 cb = *(const f32x4*)(polys + (size_t)n * 8 + 4);
  const float av[4] = {0.0f, 0.33333334f, 0.66666669f, 1.0f};
#pragma unroll
  for (int s = 0; s < 4; ++s) {
    float a1 = av[s], a2 = a1 * a1, a3 = a2 * a1;
    float v0 = ca.x * a3 + ca.y * a2 + ca.z * a1 + ca.w;
    float v1 = cb.x * a3 + cb.y * a2 + cb.z * a1 + cb.w;
    float pt0 = 2.0f * v1 - 1.0f;
    float pt1 = 2.0f * v0 - 1.0f;
    outp[(size_t)n * 8 + s * 2 + 0] = pt0;
    outp[(size_t)n * 8 + s * 2 + 1] = pt1;
    wsp[(size_t)n * 8 + s * 2 + 0] = pt0;
    wsp[(size_t)n * 8 + s * 2 + 1] = pt1;
  }
}

// ---------------------------------------------------------------------------
// Kernel 2: permute Wk -> fragment-linear bf16 W2s[t>>3][o][t&7]
__global__ void k_permwk(const float* __restrict__ Wk,
                         unsigned short* __restrict__ W2s) {
  int tid = blockIdx.x * 256 + threadIdx.x;
  if (tid >= (KD / 8) * NC) return;      // 294912
  int o = tid & 255;
  int th = tid >> 8;                     // 0..1151  (= t>>3)
  int r = th >> 5;                       // sample slot 0..35
  int cbase = (th & 31) * 8;
  int np = r / 9;
  int kl = r - np * 9;
  int kk = kl / 3;
  int ll = kl - kk * 3;
  const float* src = Wk + (size_t)o * KD + (size_t)(np * 256 + cbase) * 9 + kk * 3 + ll;
  ushortx8 v;
#pragma unroll
  for (int j = 0; j < 8; ++j) v[j] = f2bf(src[(size_t)j * 9]);
  *(ushortx8*)(W2s + (size_t)th * 2048 + o * 8) = v;
}

// Kernel 2b: permute Wp -> fragment-linear bf16 WPs[j>>3][o][j&7]
__global__ void k_permwp(const float* __restrict__ Wp,
                         unsigned short* __restrict__ WPs) {
  int tid = blockIdx.x * 256 + threadIdx.x;
  if (tid >= 32 * 256) return;
  int o = tid & 255;
  int th = tid >> 8;
  const float* src = Wp + (size_t)o * 256 + th * 8;
  ushortx8 v;
#pragma unroll
  for (int j = 0; j < 8; ++j) v[j] = f2bf(src[j]);
  *(ushortx8*)(WPs + (size_t)th * 2048 + o * 8) = v;
}

// ---------------------------------------------------------------------------
// Kernel 3: fused gather + GEMM1, M-tile = 64 rows, split-K over sample slots.
// EXACT round-6 structure (best measured: 107 us): K=4, 64 KB double-buffered
// A-LDS, ONE barrier per slot, launch_bounds(512,4) (spill-safe cap — rounds
// 7/8 proved tighter caps or big reg arrays spill to scratch catastrophically).
// SINGLE CHANGE vs round 6: the hot-loop LDS pack uses native (__bf16) casts
// (compiler emits v_cvt_pk_bf16_f32: 1 op / 2 values) instead of the 5-op/value
// software f2bf — bisects round 4's failure (mapping already exonerated) and,
// if innocent, removes the largest VALU block in the gather phase.
__global__ __launch_bounds__(512, 4) void k_gemm1(
    const float* __restrict__ mem, const float* __restrict__ pts,
    const unsigned short* __restrict__ W2s, const float* __restrict__ bk,
    float* __restrict__ PART, unsigned short* __restrict__ CR1, int K) {
  __shared__ __align__(16) unsigned short Alds[2 * 2048 * 8];  // 64 KB

  const int bid = blockIdx.x;
  const int x = bid & 7;
  const int kk8 = (bid >> 3) % K;
  const int j = bid / (8 * K);
  const int t = x + 8 * j;
  if (t >= 125) return;
  const int tt = 16 * x - ((x > 5) ? (x - 5) : 0) + j;   // contiguous tile id
  const int nsl = 36 / K;
  const int r0 = kk8 * nsl;

  const int tid = threadIdx.x;
  const int n0 = tt * 64;
  const int lane = tid & 63;
  const int wave = tid >> 6;   // 0..7
  const int lr = lane & 15;
  const int ksub = lane >> 4;
  const int o0 = wave * 32;

  const int gchunk = tid & 31;
  const int gm0 = tid >> 5;    // 0..15 ; tasks handle rows gm0+16*task, task 0..3

  // per-task row/batch bases
  size_t boff[4];
  int nrow[4];
#pragma unroll
  for (int task = 0; task < 4; ++task) {
    nrow[task] = n0 + gm0 + 16 * task;
    boff[task] = (size_t)(nrow[task] / NQ) * (NHW * NHW * NC);
  }

  f32x4 acc[4][2] = {};

  for (int r = r0; r < r0 + nsl; ++r) {
    const int s = r & 3;
    const int mm = r >> 2;
    // delta(a) = (1.5a-2)/32, exact in fp32; DHX = delta(mm/3), DWY = delta(mm%3)
    const int mdiv = (mm * 11) >> 5;          // mm/3 for mm in [0,9)
    const int mmod = mm - 3 * mdiv;
    const float dhx = (1.5f * (float)mdiv - 2.0f) * 0.03125f;
    const float dwy = (1.5f * (float)mmod - 2.0f) * 0.03125f;
    const int lbase = ((r - r0) & 1) * 2048;   // LDS buffer select
#pragma unroll 2
    for (int task = 0; task < 4; ++task) {
      const int m = gm0 + task * 16;
      const int n = nrow[task];
      const float* mb = mem + boff[task];
      const float p0 = pts[(size_t)n * 8 + s * 2 + 0];
      const float p1 = pts[(size_t)n * 8 + s * 2 + 1];
      // grid[...,0] (points[...,0]+delta_h) drives COLUMN; [...,1] drives ROW.
      const float gx = (p0 + dhx + 1.0f) * 0.5f * 63.0f;  // column
      const float gy = (p1 + dwy + 1.0f) * 0.5f * 63.0f;  // row
      const float x0f = floorf(gx), y0f = floorf(gy);
      const float fx = gx - x0f, fy = gy - y0f;
      const int ix0 = (int)x0f, iy0 = (int)y0f;
      const int ix1 = ix0 + 1, iy1 = iy0 + 1;
      const float vx0 = (ix0 >= 0 && ix0 < NHW) ? 1.0f : 0.0f;
      const float vx1 = (ix1 >= 0 && ix1 < NHW) ? 1.0f : 0.0f;
      const float vy0 = (iy0 >= 0 && iy0 < NHW) ? 1.0f : 0.0f;
      const float vy1 = (iy1 >= 0 && iy1 < NHW) ? 1.0f : 0.0f;
      const float w00 = (1.0f - fy) * (1.0f - fx) * vy0 * vx0;
      const float w01 = (1.0f - fy) * fx * vy0 * vx1;
      const float w10 = fy * (1.0f - fx) * vy1 * vx0;
      const float w11 = fy * fx * vy1 * vx1;
      const int cx0 = min(max(ix0, 0), NHW - 1), cx1 = min(max(ix1, 0), NHW - 1);
      const int cy0 = min(max(iy0, 0), NHW - 1), cy1 = min(max(iy1, 0), NHW - 1);
      const float* q00 = mb + (size_t)(cy0 * NHW + cx0) * NC + gchunk * 8;
      const float* q01 = mb + (size_t)(cy0 * NHW + cx1) * NC + gchunk * 8;
      const float* q10 = mb + (size_t)(cy1 * NHW + cx0) * NC + gchunk * 8;
      const float* q11 = mb + (size_t)(cy1 * NHW + cx1) * NC + gchunk * 8;
      f32x4 v00a = *(const f32x4*)q00, v00b = *(const f32x4*)(q00 + 4);
      f32x4 v01a = *(const f32x4*)q01, v01b = *(const f32x4*)(q01 + 4);
      f32x4 v10a = *(const f32x4*)q10, v10b = *(const f32x4*)(q10 + 4);
      f32x4 v11a = *(const f32x4*)q11, v11b = *(const f32x4*)(q11 + 4);
      f32x4 ra = v00a * w00 + v01a * w01 + v10a * w10 + v11a * w11;
      f32x4 rb = v00b * w00 + v01b * w01 + v10b * w10 + v11b * w11;
      bf16x8 pk;
      pk[0] = (__bf16)ra.x; pk[1] = (__bf16)ra.y;
      pk[2] = (__bf16)ra.z; pk[3] = (__bf16)ra.w;
      pk[4] = (__bf16)rb.x; pk[5] = (__bf16)rb.y;
      pk[6] = (__bf16)rb.z; pk[7] = (__bf16)rb.w;
      const int slot = lbase + gchunk * 64 + (m ^ (gchunk & 15));
      *(bf16x8*)(Alds + slot * 8) = pk;
    }
    __syncthreads();
    const size_t rbase = (size_t)r * 32;
#pragma unroll
    for (int kstep = 0; kstep < 8; ++kstep) {
      const int chunk = kstep * 4 + ksub;
      const unsigned short* bp = W2s + (rbase + chunk) * 2048 + (o0 + lr) * 8;
      ushortx8 ub0 = *(const ushortx8*)bp;
      ushortx8 ub1 = *(const ushortx8*)(bp + 128);
      bf16x8 fb0 = __builtin_bit_cast(bf16x8, ub0);
      bf16x8 fb1 = __builtin_bit_cast(bf16x8, ub1);
#pragma unroll
      for (int mf = 0; mf < 4; ++mf) {
        const int sa = lbase + chunk * 64 + ((mf * 16 + lr) ^ (chunk & 15));
        ushortx8 ua = *(const ushortx8*)(Alds + sa * 8);
        bf16x8 fa = __builtin_bit_cast(bf16x8, ua);
        acc[mf][0] = __builtin_amdgcn_mfma_f32_16x16x32_bf16(fa, fb0, acc[mf][0], 0, 0, 0);
        acc[mf][1] = __builtin_amdgcn_mfma_f32_16x16x32_bf16(fa, fb1, acc[mf][1], 0, 0, 0);
      }
    }
  }
  // epilogue. C/D: col=lane&15, row=(lane>>4)*4+reg
  if (PART) {
    float* dst = PART + (size_t)kk8 * (MR * NC);
#pragma unroll
    for (int mf = 0; mf < 4; ++mf)
#pragma unroll
      for (int nf = 0; nf < 2; ++nf) {
        const int o = o0 + nf * 16 + lr;
#pragma unroll
        for (int reg = 0; reg < 4; ++reg) {
          const int mrow = mf * 16 + ksub * 4 + reg;
          dst[(size_t)(n0 + mrow) * 256 + o] = acc[mf][nf][reg];
        }
      }
  } else {
#pragma unroll
    for (int mf = 0; mf < 4; ++mf)
#pragma unroll
      for (int nf = 0; nf < 2; ++nf) {
        const int o = o0 + nf * 16 + lr;
        const float bko = bk[o];
#pragma unroll
        for (int reg = 0; reg < 4; ++reg) {
          const int mrow = mf * 16 + ksub * 4 + reg;
          float v = acc[mf][nf][reg] + bko;
          v = v > 0.0f ? v : 0.0f;
          CR1[(size_t)(n0 + mrow) * 256 + o] = f2bf(v);
        }
      }
  }
}

// ---------------------------------------------------------------------------
// Kernel 3b: reduce K partials + bias + relu -> bf16 CR1
__global__ __launch_bounds__(256) void k_red(
    const float* __restrict__ PART, const float* __restrict__ bk,
    unsigned short* __restrict__ CR1, int K) {
  int gid = blockIdx.x * 256 + threadIdx.x;     // one f32x4 (4 outputs) each
  size_t idx4 = (size_t)gid * 4;
  if (idx4 >= (size_t)MR * NC) return;
  f32x4 sum = *(const f32x4*)(PART + idx4);
  for (int k = 1; k < K; ++k)
    sum += *(const f32x4*)(PART + (size_t)k * (MR * NC) + idx4);
  f32x4 bv = *(const f32x4*)(bk + (idx4 & 255));
  sum += bv;
  ushortx4 pk;
#pragma unroll
  for (int e = 0; e < 4; ++e) {
    float v = sum[e] > 0.0f ? sum[e] : 0.0f;
    pk[e] = f2bf(v);
  }
  *(ushortx4*)(CR1 + idx4) = pk;
}

// ---------------------------------------------------------------------------
// Kernel 4: GEMM2  out[n,o] = sum_j CR1[n,j]*Wp[o,j] + bp[o]  (16-row tiles)
__global__ __launch_bounds__(256) void k_gemm2(
    const unsigned short* __restrict__ CR1, const unsigned short* __restrict__ WPs,
    const float* __restrict__ bp, float* __restrict__ outc) {
  const int tid = threadIdx.x;
  const int n0 = blockIdx.x * 16;
  const int lane = tid & 63;
  const int wave = tid >> 6;  // 0..3
  const int lr = lane & 15;
  const int ksub = lane >> 4;
  const int o0 = wave * 64;
  f32x4 acc[4] = {};
#pragma unroll
  for (int kstep = 0; kstep < 8; ++kstep) {
    const int t0 = kstep * 32 + ksub * 8;
    ushortx8 ua0 = *(const ushortx8*)(CR1 + (size_t)(n0 + lr) * 256 + t0);
    bf16x8 fa0 = __builtin_bit_cast(bf16x8, ua0);
    const int chunk = kstep * 4 + ksub;
#pragma unroll
    for (int nf = 0; nf < 4; ++nf) {
      ushortx8 ub = *(const ushortx8*)(WPs + (size_t)chunk * 2048 + (o0 + nf * 16 + lr) * 8);
      bf16x8 fb = __builtin_bit_cast(bf16x8, ub);
      acc[nf] = __builtin_amdgcn_mfma_f32_16x16x32_bf16(fa0, fb, acc[nf], 0, 0, 0);
    }
  }
#pragma unroll
  for (int nf = 0; nf < 4; ++nf) {
    const int o = o0 + nf * 16 + lr;
    const float bpo = bp[o];
#pragma unroll
    for (int reg = 0; reg < 4; ++reg) {
      const int mrow = ksub * 4 + reg;
      outc[(size_t)(n0 + mrow) * 256 + o] = acc[nf][reg] + bpo;
    }
  }
}

// ---------------------------------------------------------------------------
extern "C" void kernel_launch(void* const* d_in, const int* in_sizes, int n_in,
                              void* d_out, int out_size, void* d_ws, size_t ws_size,
                              hipStream_t stream) {
  (void)in_sizes; (void)n_in; (void)out_size;
  const float* polys = (const float*)d_in[1];
  const float* mem   = (const float*)d_in[2];
  const float* Wk    = (const float*)d_in[4];
  const float* bk    = (const float*)d_in[5];
  const float* Wp    = (const float*)d_in[6];
  const float* bp    = (const float*)d_in[7];
  float* out = (float*)d_out;
  float* out_pts = out + (size_t)MR * NC;   // second output: points

  // ws layout
  unsigned short* W2s = (unsigned short*)d_ws;                       // 4,718,592 B
  unsigned short* WPs = (unsigned short*)((char*)d_ws + 4718592);    //   131,072 B
  float*          PTS = (float*)((char*)d_ws + 4849664);             //   256,000 B
  unsigned short* CR1 = (unsigned short*)((char*)d_ws + 5105664);    // 4,096,000 B
  const size_t PART_OFF = 9201664;
  float*          PARTp = (float*)((char*)d_ws + PART_OFF);          // K*8,192,000 B

  int K = 1;
  if (ws_size >= PART_OFF + 4ull * 8192000ull) K = 4;
  else if (ws_size >= PART_OFF + 2ull * 8192000ull) K = 2;
  float* PART = (K > 1) ? PARTp : nullptr;

  hipLaunchKernelGGL(k_points, dim3(32), dim3(256), 0, stream, polys, out_pts, PTS);
  hipLaunchKernelGGL(k_permwk, dim3(1152), dim3(256), 0, stream, Wk, W2s);
  hipLaunchKernelGGL(k_permwp, dim3(32), dim3(256), 0, stream, Wp, WPs);
  hipLaunchKernelGGL(k_gemm1, dim3(128 * K), dim3(512), 0, stream,
                     mem, PTS, W2s, bk, PART, CR1, K);
  if (PART)
    hipLaunchKernelGGL(k_red, dim3(2000), dim3(256), 0, stream, PART, bk, CR1, K);
  hipLaunchKernelGGL(k_gemm2, dim3(500), dim3(256), 0, stream, CR1, WPs, bp, out);
}

// Round 11
// 110.781 us; speedup vs baseline: 2.5489x; 1.0937x over previous
//
#include <hip/hip_runtime.h>

// Problem constants (fixed by setup_inputs)
#define NB 16
#define NQ 500
#define NC 256
#define NHW 64
#define MR 8000            // B*Q rows
#define KD 9216            // GEMM1 K = 36*256

typedef float f32x4 __attribute__((ext_vector_type(4)));
typedef __bf16 bf16x8 __attribute__((ext_vector_type(8)));
typedef unsigned short ushortx8 __attribute__((ext_vector_type(8)));
typedef unsigned short ushortx4 __attribute__((ext_vector_type(4)));
typedef int intx4 __attribute__((ext_vector_type(4)));

__device__ __forceinline__ unsigned short f2bf(float f) {
  unsigned int u = __builtin_bit_cast(unsigned int, f);
  u += 0x7fffu + ((u >> 16) & 1u);   // round-to-nearest-even
  return (unsigned short)(u >> 16);
}
#define BF2F(u) __builtin_bit_cast(float, (unsigned int)((unsigned int)(u) << 16))

// ---------------------------------------------------------------------------
// Kernel 0: cast memory fp32 -> bf16 (read 64 MB, write 32 MB), native casts
// (native __bf16 cast == RNE, verified bit-identical to f2bf in round 10).
__global__ __launch_bounds__(256) void k_cast(const float* __restrict__ mem,
                                              unsigned short* __restrict__ memb) {
  size_t gid = (size_t)blockIdx.x * 256 + threadIdx.x;   // 2,097,152 threads
  const float* s = mem + gid * 8;
  f32x4 a = *(const f32x4*)s, b = *(const f32x4*)(s + 4);
  bf16x8 pk;
  pk[0] = (__bf16)a.x; pk[1] = (__bf16)a.y; pk[2] = (__bf16)a.z; pk[3] = (__bf16)a.w;
  pk[4] = (__bf16)b.x; pk[5] = (__bf16)b.y; pk[6] = (__bf16)b.z; pk[7] = (__bf16)b.w;
  *(bf16x8*)(memb + gid * 8) = pk;
}

// ---------------------------------------------------------------------------
// Kernel 1 (fused): blocks 0..1151 permute Wk -> W2s[t>>3][o][t&7];
//                   blocks 1152..1183 permute Wp -> WPs[j>>3][o][j&7]
__global__ void k_prew(const float* __restrict__ Wk, const float* __restrict__ Wp,
                       unsigned short* __restrict__ W2s,
                       unsigned short* __restrict__ WPs) {
  int bid = blockIdx.x;
  if (bid < 1152) {
    int tid = bid * 256 + threadIdx.x;           // < 294912 exactly
    int o = tid & 255;
    int th = tid >> 8;                           // 0..1151  (= t>>3)
    int r = th >> 5;                             // sample slot 0..35
    int cbase = (th & 31) * 8;
    int np = r / 9;
    int kl = r - np * 9;
    int kk = kl / 3;
    int ll = kl - kk * 3;
    const float* src = Wk + (size_t)o * KD + (size_t)(np * 256 + cbase) * 9 + kk * 3 + ll;
    ushortx8 v;
#pragma unroll
    for (int j = 0; j < 8; ++j) v[j] = f2bf(src[(size_t)j * 9]);
    *(ushortx8*)(W2s + (size_t)th * 2048 + o * 8) = v;
  } else {
    int tid = (bid - 1152) * 256 + threadIdx.x;  // < 8192 exactly
    int o = tid & 255;
    int th = tid >> 8;
    const float* src = Wp + (size_t)o * 256 + th * 8;
    ushortx8 v;
#pragma unroll
    for (int j = 0; j < 8; ++j) v[j] = f2bf(src[j]);
    *(ushortx8*)(WPs + (size_t)th * 2048 + o * 8) = v;
  }
}

// ---------------------------------------------------------------------------
// Kernel 2 (fused): blocks 0..1124 -> weight/offset table WTS[r][n] (32 B:
// {w00,w01,w10,w11, off00,off01,off10,off11}), gated by wts != nullptr;
// blocks 1125..1156 -> points outputs (out_pts + PTS ws copy).
// All fp32 formulas are VERBATIM from the verified round-10 k_gemm1/k_points —
// identical ops => bit-identical values.
__global__ void k_wts(const float* __restrict__ polys, float* __restrict__ outp,
                      float* __restrict__ wsp, float* __restrict__ wts) {
  int bid = blockIdx.x;
  if (bid < 1125) {
    if (!wts) return;
    int e = bid * 256 + threadIdx.x;             // < 288000 exactly
    int r = e / 8000;                            // 0..35
    int n = e - r * 8000;
    int s = r & 3;
    int mm = r >> 2;
    int mdiv = (mm * 11) >> 5;                   // mm/3 for mm in [0,9)
    int mmod = mm - 3 * mdiv;
    float dhx = (1.5f * (float)mdiv - 2.0f) * 0.03125f;
    float dwy = (1.5f * (float)mmod - 2.0f) * 0.03125f;
    // inline poly eval for component s (identical ops to k_points):
    // a1 = {0, 0.33333334, 2*0.33333334, 1.0} — s*0.33333334f is bit-exact for
    // s<3; s==3 forced to 1.0f (3*0.33333334f != 1.0f).
    f32x4 ca = *(const f32x4*)(polys + (size_t)n * 8);
    f32x4 cb = *(const f32x4*)(polys + (size_t)n * 8 + 4);
    float a1 = (s == 3) ? 1.0f : (float)s * 0.33333334f;
    float a2 = a1 * a1, a3 = a2 * a1;
    float v0 = ca.x * a3 + ca.y * a2 + ca.z * a1 + ca.w;
    float v1 = cb.x * a3 + cb.y * a2 + cb.z * a1 + cb.w;
    float p0 = 2.0f * v1 - 1.0f;
    float p1 = 2.0f * v0 - 1.0f;
    const float gx = (p0 + dhx + 1.0f) * 0.5f * 63.0f;  // column
    const float gy = (p1 + dwy + 1.0f) * 0.5f * 63.0f;  // row
    const float x0f = floorf(gx), y0f = floorf(gy);
    const float fx = gx - x0f, fy = gy - y0f;
    const int ix0 = (int)x0f, iy0 = (int)y0f;
    const int ix1 = ix0 + 1, iy1 = iy0 + 1;
    const float vx0 = (ix0 >= 0 && ix0 < NHW) ? 1.0f : 0.0f;
    const float vx1 = (ix1 >= 0 && ix1 < NHW) ? 1.0f : 0.0f;
    const float vy0 = (iy0 >= 0 && iy0 < NHW) ? 1.0f : 0.0f;
    const float vy1 = (iy1 >= 0 && iy1 < NHW) ? 1.0f : 0.0f;
    const float w00 = (1.0f - fy) * (1.0f - fx) * vy0 * vx0;
    const float w01 = (1.0f - fy) * fx * vy0 * vx1;
    const float w10 = fy * (1.0f - fx) * vy1 * vx0;
    const float w11 = fy * fx * vy1 * vx1;
    const int cx0 = min(max(ix0, 0), NHW - 1), cx1 = min(max(ix1, 0), NHW - 1);
    const int cy0 = min(max(iy0, 0), NHW - 1), cy1 = min(max(iy1, 0), NHW - 1);
    float* dst = wts + (size_t)e * 8;
    f32x4 wv; wv.x = w00; wv.y = w01; wv.z = w10; wv.w = w11;
    intx4 ov;
    ov.x = (cy0 * NHW + cx0) * NC; ov.y = (cy0 * NHW + cx1) * NC;
    ov.z = (cy1 * NHW + cx0) * NC; ov.w = (cy1 * NHW + cx1) * NC;
    *(f32x4*)dst = wv;
    *(intx4*)(dst + 4) = ov;
  } else {
    int n = (bid - 1125) * 256 + threadIdx.x;
    if (n >= MR) return;
    f32x4 ca = *(const f32x4*)(polys + (size_t)n * 8);
    f32x4 cb = *(const f32x4*)(polys + (size_t)n * 8 + 4);
    const float av[4] = {0.0f, 0.33333334f, 0.66666669f, 1.0f};
#pragma unroll
    for (int s = 0; s < 4; ++s) {
      float a1 = av[s], a2 = a1 * a1, a3 = a2 * a1;
      float v0 = ca.x * a3 + ca.y * a2 + ca.z * a1 + ca.w;
      float v1 = cb.x * a3 + cb.y * a2 + cb.z * a1 + cb.w;
      float pt0 = 2.0f * v1 - 1.0f;
      float pt1 = 2.0f * v0 - 1.0f;
      outp[(size_t)n * 8 + s * 2 + 0] = pt0;
      outp[(size_t)n * 8 + s * 2 + 1] = pt1;
      wsp[(size_t)n * 8 + s * 2 + 0] = pt0;
      wsp[(size_t)n * 8 + s * 2 + 1] = pt1;
    }
  }
}

// ---------------------------------------------------------------------------
// Kernel 3: fused gather + GEMM1. Round-6 structure (best: K=4, 64 KB dbuf
// A-LDS, ONE barrier/slot, launch_bounds(512,4) — the only spill-safe cap).
// CHANGES vs round 10: gather reads bf16 memory (4x 16B corner loads, BF2F
// expand, fp32 blend — halves gather L1 bytes, the dominant modeled cost);
// weights/offsets come from the precomputed WTS table when USE_WTS.
template <bool USE_WTS>
__global__ __launch_bounds__(512, 4) void k_gemm1(
    const unsigned short* __restrict__ memb, const float* __restrict__ pts,
    const float* __restrict__ wts, const unsigned short* __restrict__ W2s,
    const float* __restrict__ bk, float* __restrict__ PART,
    unsigned short* __restrict__ CR1, int K) {
  __shared__ __align__(16) unsigned short Alds[2 * 2048 * 8];  // 64 KB

  const int bid = blockIdx.x;
  const int x = bid & 7;
  const int kk8 = (bid >> 3) % K;
  const int j = bid / (8 * K);
  const int t = x + 8 * j;
  if (t >= 125) return;
  const int tt = 16 * x - ((x > 5) ? (x - 5) : 0) + j;   // contiguous tile id
  const int nsl = 36 / K;
  const int r0 = kk8 * nsl;

  const int tid = threadIdx.x;
  const int n0 = tt * 64;
  const int lane = tid & 63;
  const int wave = tid >> 6;   // 0..7
  const int lr = lane & 15;
  const int ksub = lane >> 4;
  const int o0 = wave * 32;

  const int gchunk = tid & 31;
  const int gm0 = tid >> 5;    // 0..15 ; tasks handle rows gm0+16*task

  size_t boff[4];
  int nrow[4];
#pragma unroll
  for (int task = 0; task < 4; ++task) {
    nrow[task] = n0 + gm0 + 16 * task;
    boff[task] = (size_t)(nrow[task] / NQ) * (NHW * NHW * NC);
  }

  f32x4 acc[4][2] = {};

  for (int r = r0; r < r0 + nsl; ++r) {
    const int lbase = ((r - r0) & 1) * 2048;   // LDS buffer select
    float dhx = 0.0f, dwy = 0.0f;
    int s = 0;
    if (!USE_WTS) {
      s = r & 3;
      const int mm = r >> 2;
      const int mdiv = (mm * 11) >> 5;
      const int mmod = mm - 3 * mdiv;
      dhx = (1.5f * (float)mdiv - 2.0f) * 0.03125f;
      dwy = (1.5f * (float)mmod - 2.0f) * 0.03125f;
    }
#pragma unroll 2
    for (int task = 0; task < 4; ++task) {
      const int m = gm0 + task * 16;
      const int n = nrow[task];
      float w00, w01, w10, w11;
      int o00, o01, o10, o11;
      if (USE_WTS) {
        const float* we = wts + ((size_t)r * 8000 + n) * 8;
        f32x4 wv = *(const f32x4*)we;
        intx4 ov = *(const intx4*)(we + 4);
        w00 = wv.x; w01 = wv.y; w10 = wv.z; w11 = wv.w;
        o00 = ov.x; o01 = ov.y; o10 = ov.z; o11 = ov.w;
      } else {
        const float p0 = pts[(size_t)n * 8 + s * 2 + 0];
        const float p1 = pts[(size_t)n * 8 + s * 2 + 1];
        const float gx = (p0 + dhx + 1.0f) * 0.5f * 63.0f;  // column
        const float gy = (p1 + dwy + 1.0f) * 0.5f * 63.0f;  // row
        const float x0f = floorf(gx), y0f = floorf(gy);
        const float fx = gx - x0f, fy = gy - y0f;
        const int ix0 = (int)x0f, iy0 = (int)y0f;
        const int ix1 = ix0 + 1, iy1 = iy0 + 1;
        const float vx0 = (ix0 >= 0 && ix0 < NHW) ? 1.0f : 0.0f;
        const float vx1 = (ix1 >= 0 && ix1 < NHW) ? 1.0f : 0.0f;
        const float vy0 = (iy0 >= 0 && iy0 < NHW) ? 1.0f : 0.0f;
        const float vy1 = (iy1 >= 0 && iy1 < NHW) ? 1.0f : 0.0f;
        w00 = (1.0f - fy) * (1.0f - fx) * vy0 * vx0;
        w01 = (1.0f - fy) * fx * vy0 * vx1;
        w10 = fy * (1.0f - fx) * vy1 * vx0;
        w11 = fy * fx * vy1 * vx1;
        const int cx0 = min(max(ix0, 0), NHW - 1), cx1 = min(max(ix1, 0), NHW - 1);
        const int cy0 = min(max(iy0, 0), NHW - 1), cy1 = min(max(iy1, 0), NHW - 1);
        o00 = (cy0 * NHW + cx0) * NC; o01 = (cy0 * NHW + cx1) * NC;
        o10 = (cy1 * NHW + cx0) * NC; o11 = (cy1 * NHW + cx1) * NC;
      }
      const unsigned short* mb = memb + boff[task] + gchunk * 8;
      ushortx8 u00 = *(const ushortx8*)(mb + o00);
      ushortx8 u01 = *(const ushortx8*)(mb + o01);
      ushortx8 u10 = *(const ushortx8*)(mb + o10);
      ushortx8 u11 = *(const ushortx8*)(mb + o11);
      f32x4 ra, rb;
#pragma unroll
      for (int jj = 0; jj < 4; ++jj) {
        ra[jj] = BF2F(u00[jj]) * w00 + BF2F(u01[jj]) * w01 +
                 BF2F(u10[jj]) * w10 + BF2F(u11[jj]) * w11;
        rb[jj] = BF2F(u00[jj + 4]) * w00 + BF2F(u01[jj + 4]) * w01 +
                 BF2F(u10[jj + 4]) * w10 + BF2F(u11[jj + 4]) * w11;
      }
      bf16x8 pk;
      pk[0] = (__bf16)ra.x; pk[1] = (__bf16)ra.y;
      pk[2] = (__bf16)ra.z; pk[3] = (__bf16)ra.w;
      pk[4] = (__bf16)rb.x; pk[5] = (__bf16)rb.y;
      pk[6] = (__bf16)rb.z; pk[7] = (__bf16)rb.w;
      const int slot = lbase + gchunk * 64 + (m ^ (gchunk & 15));
      *(bf16x8*)(Alds + slot * 8) = pk;
    }
    __syncthreads();
    const size_t rbase = (size_t)r * 32;
#pragma unroll
    for (int kstep = 0; kstep < 8; ++kstep) {
      const int chunk = kstep * 4 + ksub;
      const unsigned short* bp = W2s + (rbase + chunk) * 2048 + (o0 + lr) * 8;
      ushortx8 ub0 = *(const ushortx8*)bp;
      ushortx8 ub1 = *(const ushortx8*)(bp + 128);
      bf16x8 fb0 = __builtin_bit_cast(bf16x8, ub0);
      bf16x8 fb1 = __builtin_bit_cast(bf16x8, ub1);
#pragma unroll
      for (int mf = 0; mf < 4; ++mf) {
        const int sa = lbase + chunk * 64 + ((mf * 16 + lr) ^ (chunk & 15));
        ushortx8 ua = *(const ushortx8*)(Alds + sa * 8);
        bf16x8 fa = __builtin_bit_cast(bf16x8, ua);
        acc[mf][0] = __builtin_amdgcn_mfma_f32_16x16x32_bf16(fa, fb0, acc[mf][0], 0, 0, 0);
        acc[mf][1] = __builtin_amdgcn_mfma_f32_16x16x32_bf16(fa, fb1, acc[mf][1], 0, 0, 0);
      }
    }
  }
  // epilogue. C/D: col=lane&15, row=(lane>>4)*4+reg
  if (PART) {
    float* dst = PART + (size_t)kk8 * (MR * NC);
#pragma unroll
    for (int mf = 0; mf < 4; ++mf)
#pragma unroll
      for (int nf = 0; nf < 2; ++nf) {
        const int o = o0 + nf * 16 + lr;
#pragma unroll
        for (int reg = 0; reg < 4; ++reg) {
          const int mrow = mf * 16 + ksub * 4 + reg;
          dst[(size_t)(n0 + mrow) * 256 + o] = acc[mf][nf][reg];
        }
      }
  } else {
#pragma unroll
    for (int mf = 0; mf < 4; ++mf)
#pragma unroll
      for (int nf = 0; nf < 2; ++nf) {
        const int o = o0 + nf * 16 + lr;
        const float bko = bk[o];
#pragma unroll
        for (int reg = 0; reg < 4; ++reg) {
          const int mrow = mf * 16 + ksub * 4 + reg;
          float v = acc[mf][nf][reg] + bko;
          v = v > 0.0f ? v : 0.0f;
          CR1[(size_t)(n0 + mrow) * 256 + o] = f2bf(v);
        }
      }
  }
}

// ---------------------------------------------------------------------------
// Kernel 3b: reduce K partials + bias + relu -> bf16 CR1
__global__ __launch_bounds__(256) void k_red(
    const float* __restrict__ PART, const float* __restrict__ bk,
    unsigned short* __restrict__ CR1, int K) {
  int gid = blockIdx.x * 256 + threadIdx.x;     // one f32x4 (4 outputs) each
  size_t idx4 = (size_t)gid * 4;
  if (idx4 >= (size_t)MR * NC) return;
  f32x4 sum = *(const f32x4*)(PART + idx4);
  for (int k = 1; k < K; ++k)
    sum += *(const f32x4*)(PART + (size_t)k * (MR * NC) + idx4);
  f32x4 bv = *(const f32x4*)(bk + (idx4 & 255));
  sum += bv;
  ushortx4 pk;
#pragma unroll
  for (int e = 0; e < 4; ++e) {
    float v = sum[e] > 0.0f ? sum[e] : 0.0f;
    pk[e] = f2bf(v);
  }
  *(ushortx4*)(CR1 + idx4) = pk;
}

// ---------------------------------------------------------------------------
// Kernel 4: GEMM2  out[n,o] = sum_j CR1[n,j]*Wp[o,j] + bp[o]  (16-row tiles)
__global__ __launch_bounds__(256) void k_gemm2(
    const unsigned short* __restrict__ CR1, const unsigned short* __restrict__ WPs,
    const float* __restrict__ bp, float* __restrict__ outc) {
  const int tid = threadIdx.x;
  const int n0 = blockIdx.x * 16;
  const int lane = tid & 63;
  const int wave = tid >> 6;  // 0..3
  const int lr = lane & 15;
  const int ksub = lane >> 4;
  const int o0 = wave * 64;
  f32x4 acc[4] = {};
#pragma unroll
  for (int kstep = 0; kstep < 8; ++kstep) {
    const int t0 = kstep * 32 + ksub * 8;
    ushortx8 ua0 = *(const ushortx8*)(CR1 + (size_t)(n0 + lr) * 256 + t0);
    bf16x8 fa0 = __builtin_bit_cast(bf16x8, ua0);
    const int chunk = kstep * 4 + ksub;
#pragma unroll
    for (int nf = 0; nf < 4; ++nf) {
      ushortx8 ub = *(const ushortx8*)(WPs + (size_t)chunk * 2048 + (o0 + nf * 16 + lr) * 8);
      bf16x8 fb = __builtin_bit_cast(bf16x8, ub);
      acc[nf] = __builtin_amdgcn_mfma_f32_16x16x32_bf16(fa0, fb, acc[nf], 0, 0, 0);
    }
  }
#pragma unroll
  for (int nf = 0; nf < 4; ++nf) {
    const int o = o0 + nf * 16 + lr;
    const float bpo = bp[o];
#pragma unroll
    for (int reg = 0; reg < 4; ++reg) {
      const int mrow = ksub * 4 + reg;
      outc[(size_t)(n0 + mrow) * 256 + o] = acc[nf][reg] + bpo;
    }
  }
}

// ---------------------------------------------------------------------------
extern "C" void kernel_launch(void* const* d_in, const int* in_sizes, int n_in,
                              void* d_out, int out_size, void* d_ws, size_t ws_size,
                              hipStream_t stream) {
  (void)in_sizes; (void)n_in; (void)out_size;
  const float* polys = (const float*)d_in[1];
  const float* mem   = (const float*)d_in[2];
  const float* Wk    = (const float*)d_in[4];
  const float* bk    = (const float*)d_in[5];
  const float* Wp    = (const float*)d_in[6];
  const float* bp    = (const float*)d_in[7];
  float* out = (float*)d_out;
  float* out_pts = out + (size_t)MR * NC;   // second output: points

  // ws layout: base block, then [WTS?] + MEMB + PART (K=4)
  unsigned short* W2s = (unsigned short*)d_ws;                       // 4,718,592 B
  unsigned short* WPs = (unsigned short*)((char*)d_ws + 4718592);    //   131,072 B
  float*          PTS = (float*)((char*)d_ws + 4849664);             //   256,000 B
  unsigned short* CR1 = (unsigned short*)((char*)d_ws + 5105664);    // 4,096,000 B
  const size_t BASE_END = 9201664;
  const size_t WTS_SZ  = 9216000ull;      // 288000 * 32 B
  const size_t MEMB_SZ = 33554432ull;     // 16*4096*256 bf16
  const size_t PART_SZ = 8192000ull;      // 8000*256 fp32 per split
  const int K = 4;

  // ws >= BASE_END + MEMB_SZ + 4*PART_SZ (75.5 MB) is PROVEN (round 4 took the
  // bf branch at this threshold). WTS is bonus if ws >= 84.74 MB.
  bool use_wts = (ws_size >= BASE_END + WTS_SZ + MEMB_SZ + 4 * PART_SZ);
  size_t memb_off = use_wts ? (BASE_END + WTS_SZ) : BASE_END;
  float*          WTS  = use_wts ? (float*)((char*)d_ws + BASE_END) : nullptr;
  unsigned short* MEMB = (unsigned short*)((char*)d_ws + memb_off);
  float*          PART = (float*)((char*)d_ws + memb_off + MEMB_SZ);

  hipLaunchKernelGGL(k_wts, dim3(1157), dim3(256), 0, stream, polys, out_pts, PTS, WTS);
  hipLaunchKernelGGL(k_cast, dim3(8192), dim3(256), 0, stream, mem, MEMB);
  hipLaunchKernelGGL(k_prew, dim3(1184), dim3(256), 0, stream, Wk, Wp, W2s, WPs);
  if (use_wts)
    hipLaunchKernelGGL(k_gemm1<true>, dim3(128 * K), dim3(512), 0, stream,
                       MEMB, PTS, WTS, W2s, bk, PART, CR1, K);
  else
    hipLaunchKernelGGL(k_gemm1<false>, dim3(128 * K), dim3(512), 0, stream,
                       MEMB, PTS, WTS, W2s, bk, PART, CR1, K);
  hipLaunchKernelGGL(k_red, dim3(2000), dim3(256), 0, stream, PART, bk, CR1, K);
  hipLaunchKernelGGL(k_gemm2, dim3(500), dim3(256), 0, stream, CR1, WPs, bp, out);
}

// Round 14
// 109.763 us; speedup vs baseline: 2.5725x; 1.0093x over previous
//
#include <hip/hip_runtime.h>

// Problem constants (fixed by setup_inputs)
#define NB 16
#define NQ 500
#define NC 256
#define NHW 64
#define MR 8000            // B*Q rows
#define KD 9216            // GEMM1 K = 36*256

typedef float f32x4 __attribute__((ext_vector_type(4)));
typedef __bf16 bf16x8 __attribute__((ext_vector_type(8)));
typedef unsigned short ushortx8 __attribute__((ext_vector_type(8)));
typedef unsigned int uintx4 __attribute__((ext_vector_type(4)));
typedef int intx4 __attribute__((ext_vector_type(4)));

__device__ __forceinline__ unsigned short f2bf(float f) {
  unsigned int u = __builtin_bit_cast(unsigned int, f);
  u += 0x7fffu + ((u >> 16) & 1u);   // round-to-nearest-even
  return (unsigned short)(u >> 16);
}
#define U2F(u) __builtin_bit_cast(float, (unsigned int)(u))

// ---------------------------------------------------------------------------
// Kernel 1 (fused prep): grid-concatenated independent phases.
//   [0, 8192)          : cast memory fp32 -> bf16 (verified native RNE casts)
//   [8192, 9344)       : permute Wk -> W2s[t>>3][o][t&7]
//   [9344, 9376)       : permute Wp -> WPs[j>>3][o][j&7]
//   [9376, 10501)      : weight/offset table WTS[r][n] (gated on wts!=null)
//   [10501, 10533)     : points outputs (out_pts + PTS ws copy)
__global__ void k_prep(const float* __restrict__ mem, unsigned short* __restrict__ memb,
                       const float* __restrict__ Wk, const float* __restrict__ Wp,
                       unsigned short* __restrict__ W2s, unsigned short* __restrict__ WPs,
                       const float* __restrict__ polys, float* __restrict__ outp,
                       float* __restrict__ wsp, float* __restrict__ wts) {
  const int bid = blockIdx.x;
  if (bid < 8192) {
    size_t gid = (size_t)bid * 256 + threadIdx.x;
    const float* s = mem + gid * 8;
    f32x4 a = *(const f32x4*)s, b = *(const f32x4*)(s + 4);
    bf16x8 pk;
    pk[0] = (__bf16)a.x; pk[1] = (__bf16)a.y; pk[2] = (__bf16)a.z; pk[3] = (__bf16)a.w;
    pk[4] = (__bf16)b.x; pk[5] = (__bf16)b.y; pk[6] = (__bf16)b.z; pk[7] = (__bf16)b.w;
    *(bf16x8*)(memb + gid * 8) = pk;
  } else if (bid < 9344) {
    int tid = (bid - 8192) * 256 + threadIdx.x;  // < 294912 exactly
    int o = tid & 255;
    int th = tid >> 8;                           // 0..1151  (= t>>3)
    int r = th >> 5;                             // sample slot 0..35
    int cbase = (th & 31) * 8;
    int np = r / 9;
    int kl = r - np * 9;
    int kk = kl / 3;
    int ll = kl - kk * 3;
    const float* src = Wk + (size_t)o * KD + (size_t)(np * 256 + cbase) * 9 + kk * 3 + ll;
    ushortx8 v;
#pragma unroll
    for (int j = 0; j < 8; ++j) v[j] = f2bf(src[(size_t)j * 9]);
    *(ushortx8*)(W2s + (size_t)th * 2048 + o * 8) = v;
  } else if (bid < 9376) {
    int tid = (bid - 9344) * 256 + threadIdx.x;  // < 8192 exactly
    int o = tid & 255;
    int th = tid >> 8;
    const float* src = Wp + (size_t)o * 256 + th * 8;
    ushortx8 v;
#pragma unroll
    for (int j = 0; j < 8; ++j) v[j] = f2bf(src[j]);
    *(ushortx8*)(WPs + (size_t)th * 2048 + o * 8) = v;
  } else if (bid < 10501) {
    if (!wts) return;
    int e = (bid - 9376) * 256 + threadIdx.x;    // < 288000 exactly
    int r = e / 8000;                            // 0..35
    int n = e - r * 8000;
    int s = r & 3;
    int mm = r >> 2;
    int mdiv = (mm * 11) >> 5;                   // mm/3 for mm in [0,9)
    int mmod = mm - 3 * mdiv;
    float dhx = (1.5f * (float)mdiv - 2.0f) * 0.03125f;
    float dwy = (1.5f * (float)mmod - 2.0f) * 0.03125f;
    f32x4 ca = *(const f32x4*)(polys + (size_t)n * 8);
    f32x4 cb = *(const f32x4*)(polys + (size_t)n * 8 + 4);
    float a1 = (s == 3) ? 1.0f : (float)s * 0.33333334f;
    float a2 = a1 * a1, a3 = a2 * a1;
    float v0 = ca.x * a3 + ca.y * a2 + ca.z * a1 + ca.w;
    float v1 = cb.x * a3 + cb.y * a2 + cb.z * a1 + cb.w;
    float p0 = 2.0f * v1 - 1.0f;
    float p1 = 2.0f * v0 - 1.0f;
    const float gx = (p0 + dhx + 1.0f) * 0.5f * 63.0f;  // column
    const float gy = (p1 + dwy + 1.0f) * 0.5f * 63.0f;  // row
    const float x0f = floorf(gx), y0f = floorf(gy);
    const float fx = gx - x0f, fy = gy - y0f;
    const int ix0 = (int)x0f, iy0 = (int)y0f;
    const int ix1 = ix0 + 1, iy1 = iy0 + 1;
    const float vx0 = (ix0 >= 0 && ix0 < NHW) ? 1.0f : 0.0f;
    const float vx1 = (ix1 >= 0 && ix1 < NHW) ? 1.0f : 0.0f;
    const float vy0 = (iy0 >= 0 && iy0 < NHW) ? 1.0f : 0.0f;
    const float vy1 = (iy1 >= 0 && iy1 < NHW) ? 1.0f : 0.0f;
    const float w00 = (1.0f - fy) * (1.0f - fx) * vy0 * vx0;
    const float w01 = (1.0f - fy) * fx * vy0 * vx1;
    const float w10 = fy * (1.0f - fx) * vy1 * vx0;
    const float w11 = fy * fx * vy1 * vx1;
    const int cx0 = min(max(ix0, 0), NHW - 1), cx1 = min(max(ix1, 0), NHW - 1);
    const int cy0 = min(max(iy0, 0), NHW - 1), cy1 = min(max(iy1, 0), NHW - 1);
    float* dst = wts + (size_t)e * 8;
    f32x4 wv; wv.x = w00; wv.y = w01; wv.z = w10; wv.w = w11;
    intx4 ov;
    ov.x = (cy0 * NHW + cx0) * NC; ov.y = (cy0 * NHW + cx1) * NC;
    ov.z = (cy1 * NHW + cx0) * NC; ov.w = (cy1 * NHW + cx1) * NC;
    *(f32x4*)dst = wv;
    *(intx4*)(dst + 4) = ov;
  } else {
    int n = (bid - 10501) * 256 + threadIdx.x;
    if (n >= MR) return;
    f32x4 ca = *(const f32x4*)(polys + (size_t)n * 8);
    f32x4 cb = *(const f32x4*)(polys + (size_t)n * 8 + 4);
    const float av[4] = {0.0f, 0.33333334f, 0.66666669f, 1.0f};
#pragma unroll
    for (int s = 0; s < 4; ++s) {
      float a1 = av[s], a2 = a1 * a1, a3 = a2 * a1;
      float v0 = ca.x * a3 + ca.y * a2 + ca.z * a1 + ca.w;
      float v1 = cb.x * a3 + cb.y * a2 + cb.z * a1 + cb.w;
      float pt0 = 2.0f * v1 - 1.0f;
      float pt1 = 2.0f * v0 - 1.0f;
      outp[(size_t)n * 8 + s * 2 + 0] = pt0;
      outp[(size_t)n * 8 + s * 2 + 1] = pt1;
      wsp[(size_t)n * 8 + s * 2 + 0] = pt0;
      wsp[(size_t)n * 8 + s * 2 + 1] = pt1;
    }
  }
}

// ---------------------------------------------------------------------------
// Kernel 2: fused gather + GEMM1. Verified round-11 structure (K=4, 64 KB
// dbuf A-LDS, ONE barrier/slot, launch_bounds(512,4) — only spill-safe cap).
// CHANGE vs round 11: blend vectorized — bf16 pairs expanded via <<16 and
// &0xFFFF0000 (1 op/elem, same count), 4-corner blend as f32x4 ops so the
// compiler emits v_pk_fma_f32 (halves blend FMA issue). Same per-element
// mul+3*fma contraction shape => bit-identical values.
template <bool USE_WTS>
__global__ __launch_bounds__(512, 4) void k_gemm1(
    const unsigned short* __restrict__ memb, const float* __restrict__ pts,
    const float* __restrict__ wts, const unsigned short* __restrict__ W2s,
    const float* __restrict__ bk, float* __restrict__ PART, int K) {
  __shared__ __align__(16) unsigned short Alds[2 * 2048 * 8];  // 64 KB

  const int bid = blockIdx.x;
  const int x = bid & 7;
  const int kk8 = (bid >> 3) % K;
  const int j = bid / (8 * K);
  const int t = x + 8 * j;
  if (t >= 125) return;
  const int tt = 16 * x - ((x > 5) ? (x - 5) : 0) + j;   // contiguous tile id
  const int nsl = 36 / K;
  const int r0 = kk8 * nsl;

  const int tid = threadIdx.x;
  const int n0 = tt * 64;
  const int lane = tid & 63;
  const int wave = tid >> 6;   // 0..7
  const int lr = lane & 15;
  const int ksub = lane >> 4;
  const int o0 = wave * 32;

  const int gchunk = tid & 31;
  const int gm0 = tid >> 5;    // 0..15 ; tasks handle rows gm0+16*task

  size_t boff[4];
  int nrow[4];
#pragma unroll
  for (int task = 0; task < 4; ++task) {
    nrow[task] = n0 + gm0 + 16 * task;
    boff[task] = (size_t)(nrow[task] / NQ) * (NHW * NHW * NC);
  }

  f32x4 acc[4][2] = {};

  for (int r = r0; r < r0 + nsl; ++r) {
    const int lbase = ((r - r0) & 1) * 2048;   // LDS buffer select
    float dhx = 0.0f, dwy = 0.0f;
    int s = 0;
    if (!USE_WTS) {
      s = r & 3;
      const int mm = r >> 2;
      const int mdiv = (mm * 11) >> 5;
      const int mmod = mm - 3 * mdiv;
      dhx = (1.5f * (float)mdiv - 2.0f) * 0.03125f;
      dwy = (1.5f * (float)mmod - 2.0f) * 0.03125f;
    }
#pragma unroll 2
    for (int task = 0; task < 4; ++task) {
      const int m = gm0 + task * 16;
      const int n = nrow[task];
      float w00, w01, w10, w11;
      int o00, o01, o10, o11;
      if (USE_WTS) {
        const float* we = wts + ((size_t)r * 8000 + n) * 8;
        f32x4 wv = *(const f32x4*)we;
        intx4 ov = *(const intx4*)(we + 4);
        w00 = wv.x; w01 = wv.y; w10 = wv.z; w11 = wv.w;
        o00 = ov.x; o01 = ov.y; o10 = ov.z; o11 = ov.w;
      } else {
        const float p0 = pts[(size_t)n * 8 + s * 2 + 0];
        const float p1 = pts[(size_t)n * 8 + s * 2 + 1];
        const float gx = (p0 + dhx + 1.0f) * 0.5f * 63.0f;  // column
        const float gy = (p1 + dwy + 1.0f) * 0.5f * 63.0f;  // row
        const float x0f = floorf(gx), y0f = floorf(gy);
        const float fx = gx - x0f, fy = gy - y0f;
        const int ix0 = (int)x0f, iy0 = (int)y0f;
        const int ix1 = ix0 + 1, iy1 = iy0 + 1;
        const float vx0 = (ix0 >= 0 && ix0 < NHW) ? 1.0f : 0.0f;
        const float vx1 = (ix1 >= 0 && ix1 < NHW) ? 1.0f : 0.0f;
        const float vy0 = (iy0 >= 0 && iy0 < NHW) ? 1.0f : 0.0f;
        const float vy1 = (iy1 >= 0 && iy1 < NHW) ? 1.0f : 0.0f;
        w00 = (1.0f - fy) * (1.0f - fx) * vy0 * vx0;
        w01 = (1.0f - fy) * fx * vy0 * vx1;
        w10 = fy * (1.0f - fx) * vy1 * vx0;
        w11 = fy * fx * vy1 * vx1;
        const int cx0 = min(max(ix0, 0), NHW - 1), cx1 = min(max(ix1, 0), NHW - 1);
        const int cy0 = min(max(iy0, 0), NHW - 1), cy1 = min(max(iy1, 0), NHW - 1);
        o00 = (cy0 * NHW + cx0) * NC; o01 = (cy0 * NHW + cx1) * NC;
        o10 = (cy1 * NHW + cx0) * NC; o11 = (cy1 * NHW + cx1) * NC;
      }
      const unsigned short* mb = memb + boff[task] + gchunk * 8;
      uintx4 u00 = *(const uintx4*)(mb + o00);
      uintx4 u01 = *(const uintx4*)(mb + o01);
      uintx4 u10 = *(const uintx4*)(mb + o10);
      uintx4 u11 = *(const uintx4*)(mb + o11);
      // expand: word w holds elems {2w (lo), 2w+1 (hi)}; ra <- elems 0..3,
      // rb <- elems 4..7
      f32x4 a00, b00, a01, b01, a10, b10, a11, b11;
      a00.x = U2F(u00.x << 16); a00.y = U2F(u00.x & 0xFFFF0000u);
      a00.z = U2F(u00.y << 16); a00.w = U2F(u00.y & 0xFFFF0000u);
      b00.x = U2F(u00.z << 16); b00.y = U2F(u00.z & 0xFFFF0000u);
      b00.z = U2F(u00.w << 16); b00.w = U2F(u00.w & 0xFFFF0000u);
      a01.x = U2F(u01.x << 16); a01.y = U2F(u01.x & 0xFFFF0000u);
      a01.z = U2F(u01.y << 16); a01.w = U2F(u01.y & 0xFFFF0000u);
      b01.x = U2F(u01.z << 16); b01.y = U2F(u01.z & 0xFFFF0000u);
      b01.z = U2F(u01.w << 16); b01.w = U2F(u01.w & 0xFFFF0000u);
      a10.x = U2F(u10.x << 16); a10.y = U2F(u10.x & 0xFFFF0000u);
      a10.z = U2F(u10.y << 16); a10.w = U2F(u10.y & 0xFFFF0000u);
      b10.x = U2F(u10.z << 16); b10.y = U2F(u10.z & 0xFFFF0000u);
      b10.z = U2F(u10.w << 16); b10.w = U2F(u10.w & 0xFFFF0000u);
      a11.x = U2F(u11.x << 16); a11.y = U2F(u11.x & 0xFFFF0000u);
      a11.z = U2F(u11.y << 16); a11.w = U2F(u11.y & 0xFFFF0000u);
      b11.x = U2F(u11.z << 16); b11.y = U2F(u11.z & 0xFFFF0000u);
      b11.z = U2F(u11.w << 16); b11.w = U2F(u11.w & 0xFFFF0000u);
      f32x4 ra = a00 * w00 + a01 * w01 + a10 * w10 + a11 * w11;
      f32x4 rb = b00 * w00 + b01 * w01 + b10 * w10 + b11 * w11;
      bf16x8 pk;
      pk[0] = (__bf16)ra.x; pk[1] = (__bf16)ra.y;
      pk[2] = (__bf16)ra.z; pk[3] = (__bf16)ra.w;
      pk[4] = (__bf16)rb.x; pk[5] = (__bf16)rb.y;
      pk[6] = (__bf16)rb.z; pk[7] = (__bf16)rb.w;
      const int slot = lbase + gchunk * 64 + (m ^ (gchunk & 15));
      *(bf16x8*)(Alds + slot * 8) = pk;
    }
    __syncthreads();
    const size_t rbase = (size_t)r * 32;
#pragma unroll
    for (int kstep = 0; kstep < 8; ++kstep) {
      const int chunk = kstep * 4 + ksub;
      const unsigned short* bp = W2s + (rbase + chunk) * 2048 + (o0 + lr) * 8;
      ushortx8 ub0 = *(const ushortx8*)bp;
      ushortx8 ub1 = *(const ushortx8*)(bp + 128);
      bf16x8 fb0 = __builtin_bit_cast(bf16x8, ub0);
      bf16x8 fb1 = __builtin_bit_cast(bf16x8, ub1);
#pragma unroll
      for (int mf = 0; mf < 4; ++mf) {
        const int sa = lbase + chunk * 64 + ((mf * 16 + lr) ^ (chunk & 15));
        ushortx8 ua = *(const ushortx8*)(Alds + sa * 8);
        bf16x8 fa = __builtin_bit_cast(bf16x8, ua);
        acc[mf][0] = __builtin_amdgcn_mfma_f32_16x16x32_bf16(fa, fb0, acc[mf][0], 0, 0, 0);
        acc[mf][1] = __builtin_amdgcn_mfma_f32_16x16x32_bf16(fa, fb1, acc[mf][1], 0, 0, 0);
      }
    }
  }
  // epilogue: fp32 partials. C/D: col=lane&15, row=(lane>>4)*4+reg
  float* dst = PART + (size_t)kk8 * (MR * NC);
#pragma unroll
  for (int mf = 0; mf < 4; ++mf)
#pragma unroll
    for (int nf = 0; nf < 2; ++nf) {
      const int o = o0 + nf * 16 + lr;
#pragma unroll
      for (int reg = 0; reg < 4; ++reg) {
        const int mrow = mf * 16 + ksub * 4 + reg;
        dst[(size_t)(n0 + mrow) * 256 + o] = acc[mf][nf][reg];
      }
    }
}

// ---------------------------------------------------------------------------
// Kernel 3: fused reduce + GEMM2 (16-row tiles).
// A-fragment built in-register: sum 4 PART slices, +bk, relu, native bf16 cast
// (== k_red's f2bf, verified). Same sum order k=0..3 as k_red => bit-identical.
__global__ __launch_bounds__(256) void k_gemm2(
    const float* __restrict__ PART, const float* __restrict__ bk,
    const unsigned short* __restrict__ WPs, const float* __restrict__ bp,
    float* __restrict__ outc) {
  const int tid = threadIdx.x;
  const int n0 = blockIdx.x * 16;
  const int lane = tid & 63;
  const int wave = tid >> 6;  // 0..3
  const int lr = lane & 15;
  const int ksub = lane >> 4;
  const int o0 = wave * 64;
  f32x4 acc[4] = {};
#pragma unroll
  for (int kstep = 0; kstep < 8; ++kstep) {
    const int t0 = kstep * 32 + ksub * 8;
    const float* base = PART + (size_t)(n0 + lr) * 256 + t0;
    f32x4 s0 = *(const f32x4*)base;
    f32x4 s1 = *(const f32x4*)(base + 4);
#pragma unroll
    for (int k = 1; k < 4; ++k) {
      const float* pk_ = base + (size_t)k * (MR * NC);
      s0 += *(const f32x4*)pk_;
      s1 += *(const f32x4*)(pk_ + 4);
    }
    s0 += *(const f32x4*)(bk + t0);
    s1 += *(const f32x4*)(bk + t0 + 4);
    bf16x8 fa;
#pragma unroll
    for (int e = 0; e < 4; ++e) {
      float v0 = s0[e] > 0.0f ? s0[e] : 0.0f;
      float v1 = s1[e] > 0.0f ? s1[e] : 0.0f;
      fa[e] = (__bf16)v0;
      fa[e + 4] = (__bf16)v1;
    }
    const int chunk = kstep * 4 + ksub;
#pragma unroll
    for (int nf = 0; nf < 4; ++nf) {
      ushortx8 ub = *(const ushortx8*)(WPs + (size_t)chunk * 2048 + (o0 + nf * 16 + lr) * 8);
      bf16x8 fb = __builtin_bit_cast(bf16x8, ub);
      acc[nf] = __builtin_amdgcn_mfma_f32_16x16x32_bf16(fa, fb, acc[nf], 0, 0, 0);
    }
  }
#pragma unroll
  for (int nf = 0; nf < 4; ++nf) {
    const int o = o0 + nf * 16 + lr;
    const float bpo = bp[o];
#pragma unroll
    for (int reg = 0; reg < 4; ++reg) {
      const int mrow = ksub * 4 + reg;
      outc[(size_t)(n0 + mrow) * 256 + o] = acc[nf][reg] + bpo;
    }
  }
}

// ---------------------------------------------------------------------------
extern "C" void kernel_launch(void* const* d_in, const int* in_sizes, int n_in,
                              void* d_out, int out_size, void* d_ws, size_t ws_size,
                              hipStream_t stream) {
  (void)in_sizes; (void)n_in; (void)out_size;
  const float* polys = (const float*)d_in[1];
  const float* mem   = (const float*)d_in[2];
  const float* Wk    = (const float*)d_in[4];
  const float* bk    = (const float*)d_in[5];
  const float* Wp    = (const float*)d_in[6];
  const float* bp    = (const float*)d_in[7];
  float* out = (float*)d_out;
  float* out_pts = out + (size_t)MR * NC;   // second output: points

  // ws layout: base block, then [WTS?] + MEMB + PART (K=4)
  unsigned short* W2s = (unsigned short*)d_ws;                       // 4,718,592 B
  unsigned short* WPs = (unsigned short*)((char*)d_ws + 4718592);    //   131,072 B
  float*          PTS = (float*)((char*)d_ws + 4849664);             //   256,000 B
  const size_t BASE_END = 9201664;        // (CR1 slot retained, now unused)
  const size_t WTS_SZ  = 9216000ull;      // 288000 * 32 B
  const size_t MEMB_SZ = 33554432ull;     // 16*4096*256 bf16
  const size_t PART_SZ = 8192000ull;      // 8000*256 fp32 per split
  const int K = 4;

  bool use_wts = (ws_size >= BASE_END + WTS_SZ + MEMB_SZ + 4 * PART_SZ);
  size_t memb_off = use_wts ? (BASE_END + WTS_SZ) : BASE_END;
  float*          WTS  = use_wts ? (float*)((char*)d_ws + BASE_END) : nullptr;
  unsigned short* MEMB = (unsigned short*)((char*)d_ws + memb_off);
  float*          PART = (float*)((char*)d_ws + memb_off + MEMB_SZ);

  hipLaunchKernelGGL(k_prep, dim3(10533), dim3(256), 0, stream,
                     mem, MEMB, Wk, Wp, W2s, WPs, polys, out_pts, PTS, WTS);
  if (use_wts)
    hipLaunchKernelGGL(k_gemm1<true>, dim3(128 * K), dim3(512), 0, stream,
                       MEMB, PTS, WTS, W2s, bk, PART, K);
  else
    hipLaunchKernelGGL(k_gemm1<false>, dim3(128 * K), dim3(512), 0, stream,
                       MEMB, PTS, WTS, W2s, bk, PART, K);
  hipLaunchKernelGGL(k_gemm2, dim3(500), dim3(256), 0, stream, PART, bk, WPs, bp, out);
}